// Round 2
// baseline (3777.780 us; speedup 1.0000x reference)
//
#include <hip/hip_runtime.h>
#include <cstdint>
#include <cstddef>

typedef unsigned short u16;
typedef __bf16 bf16x8 __attribute__((ext_vector_type(8)));
typedef float f32x4 __attribute__((ext_vector_type(4)));

constexpr int Bz = 8, Sq = 512, Hh = 8, DKd = 64, Dm = 512, Dff = 2048, NL = 4;
constexpr int TOK = Bz * Sq;               // 4096 tokens
constexpr size_t MAT = (size_t)512 * 512;  // 262144 elems per 512x512 matrix
constexpr size_t EL  = (size_t)TOK * Dm;   // 2097152 elems per activation tensor

__device__ __forceinline__ float bf2f(u16 u) {
  union { uint32_t i; float f; } v; v.i = (uint32_t)u << 16; return v.f;
}
__device__ __forceinline__ u16 f2bf(float f) {
  union { float f; uint32_t i; } v; v.f = f;
  uint32_t i = v.i;
  i += 0x7fffu + ((i >> 16) & 1u);   // round-to-nearest-even
  return (u16)(i >> 16);
}

// ---------------------------------------------------------------------------
// Generic NT GEMM: C[M,N] = A[M,K] @ Bt[N,K]^T (+bias fp32) (+relu)
// block = 256 threads = 4 waves; block tile 64(M) x 64(N); wave tile 16x64.
// MFMA 16x16x32 bf16, f32 accum, bf16 store. A/Bt are bf16.
// cmode: 0 = plain (bz*sC + row*ldc + col)
//        1 = heads   [B,H,S,DK]  (bz = b)
//        2 = heads^T [B,H,DK,S]  (bz = b)
//        3 = ctx     [B,S,H*DK]  (bz = b*8+h)
// ---------------------------------------------------------------------------
__global__ __launch_bounds__(256)
void gemm_nt(const u16* __restrict__ A, const u16* __restrict__ Bt,
             const float* __restrict__ bias, u16* __restrict__ C,
             int K, int lda, long long sA, int ldb, long long sB,
             int ldc, long long sC, int cmode, int relu)
{
  const int bz   = blockIdx.z;
  const u16* Ab  = A  + (size_t)bz * (size_t)sA;
  const u16* Bb  = Bt + (size_t)bz * (size_t)sB;
  const int wid  = threadIdx.x >> 6;
  const int lane = threadIdx.x & 63;
  const int l15  = lane & 15;
  const int quad = lane >> 4;
  const int rowA = blockIdx.y * 64 + wid * 16 + l15;
  const int colbase = blockIdx.x * 64;
  const u16* ap = Ab + (size_t)rowA * lda + quad * 8;
  const u16* bp = Bb + (size_t)(colbase + l15) * ldb + quad * 8;
  const size_t bstep = (size_t)16 * ldb;
  f32x4 a0 = {0.f, 0.f, 0.f, 0.f}, a1 = a0, a2 = a0, a3 = a0;
  for (int k0 = 0; k0 < K; k0 += 32) {
    bf16x8 af = *(const bf16x8*)(ap + k0);
    bf16x8 b0 = *(const bf16x8*)(bp + k0);
    bf16x8 b1 = *(const bf16x8*)(bp + bstep + k0);
    bf16x8 b2 = *(const bf16x8*)(bp + 2 * bstep + k0);
    bf16x8 b3 = *(const bf16x8*)(bp + 3 * bstep + k0);
    a0 = __builtin_amdgcn_mfma_f32_16x16x32_bf16(af, b0, a0, 0, 0, 0);
    a1 = __builtin_amdgcn_mfma_f32_16x16x32_bf16(af, b1, a1, 0, 0, 0);
    a2 = __builtin_amdgcn_mfma_f32_16x16x32_bf16(af, b2, a2, 0, 0, 0);
    a3 = __builtin_amdgcn_mfma_f32_16x16x32_bf16(af, b3, a3, 0, 0, 0);
  }
  const int rbase = blockIdx.y * 64 + wid * 16 + quad * 4;
  f32x4 accs[4] = {a0, a1, a2, a3};
#pragma unroll
  for (int t = 0; t < 4; ++t) {
    const int col = colbase + t * 16 + l15;
    const float bv = bias ? bias[col] : 0.f;
#pragma unroll
    for (int r = 0; r < 4; ++r) {
      float v = accs[t][r] + bv;
      if (relu) v = fmaxf(v, 0.f);
      const int grow = rbase + r;
      size_t off;
      if (cmode == 0)      off = (size_t)bz * (size_t)sC + (size_t)grow * ldc + col;
      else if (cmode == 1) off = (size_t)bz * 262144 + (size_t)(col >> 6) * 32768 + (size_t)grow * 64 + (col & 63);
      else if (cmode == 2) off = (size_t)bz * 262144 + (size_t)(col >> 6) * 32768 + (size_t)(col & 63) * 512 + grow;
      else                 off = (size_t)(bz >> 3) * 262144 + (size_t)grow * 512 + (size_t)(bz & 7) * 64 + col;
      C[off] = f2bf(v);
    }
  }
}

// 512x512 transpose, fp32 in -> bf16 out, batched over blockIdx.z
__global__ __launch_bounds__(256)
void transpose512(const float* __restrict__ in, u16* __restrict__ out)
{
  __shared__ float tile[32][33];
  const size_t base = (size_t)blockIdx.z * MAT;
  int x = blockIdx.x * 32 + threadIdx.x;
  int y = blockIdx.y * 32 + threadIdx.y;
#pragma unroll
  for (int i = 0; i < 32; i += 8)
    tile[threadIdx.y + i][threadIdx.x] = in[base + (size_t)(y + i) * 512 + x];
  __syncthreads();
  x = blockIdx.y * 32 + threadIdx.x;
  y = blockIdx.x * 32 + threadIdx.y;
#pragma unroll
  for (int i = 0; i < 32; i += 8)
    out[base + (size_t)(y + i) * 512 + x] = f2bf(tile[threadIdx.x][threadIdx.y + i]);
}

// flat fp32 -> bf16 convert
__global__ __launch_bounds__(256)
void convert_f2b(const float* __restrict__ in, u16* __restrict__ out, int n)
{
  int i = blockIdx.x * 256 + threadIdx.x;
  if (i < n) out[i] = f2bf(in[i]);
}

// out[b,s,:] = concat(x[b,s,:], x@emb_w^T + emb_b) + pos_table[s+1]  (fp32 in, bf16 out)
__global__ __launch_bounds__(256)
void embed_k(const float* __restrict__ x, const float* __restrict__ ew,
             const float* __restrict__ eb, const float* __restrict__ pos,
             u16* __restrict__ out)
{
  const int rs = blockIdx.x;          // b*512 + s
  const int s  = rs & 511;
  __shared__ float xr[32];
  const int t = threadIdx.x;
  if (t < 32) xr[t] = x[(size_t)rs * 32 + t];
  __syncthreads();
#pragma unroll
  for (int rep = 0; rep < 2; ++rep) {
    const int c = t + rep * 256;
    float v;
    if (c < 32) {
      v = xr[c];
    } else {
      const float* w = ew + (size_t)(c - 32) * 32;
      float acc = eb[c - 32];
#pragma unroll
      for (int f = 0; f < 32; ++f) acc += xr[f] * w[f];
      v = acc;
    }
    v += pos[(size_t)(s + 1) * 512 + c];
    out[(size_t)rs * 512 + c] = f2bf(v);
  }
}

// pad[b,s] = (sum_f x[b,s,f] <= -9999)  (fp32 in)
__global__ __launch_bounds__(256)
void pad_k(const float* __restrict__ x, unsigned char* __restrict__ pad)
{
  int r = blockIdx.x * 256 + threadIdx.x;
  if (r < TOK) {
    float s = 0.f;
    for (int f = 0; f < 32; ++f) s += x[(size_t)r * 32 + f];
    pad[r] = (s <= -9999.f) ? 1 : 0;
  }
}

// in-place masked, scaled softmax over rows of 512 (bf16 scores).
// row = (b*H + h)*512 + q.  type: 0/2 = pad-only, 1 = pad | causal(col>q)
__global__ __launch_bounds__(256)
void softmax_mask(u16* sc, const unsigned char* __restrict__ pad, int type)
{
  const int row = blockIdx.x;
  const int q = row & 511;
  const int b = row >> 12;            // H*S = 4096 rows per batch
  u16* p = sc + (size_t)row * 512;
  const unsigned char* pb = pad + b * 512;
  const int t = threadIdx.x;
  __shared__ float red[256];
  const int c0 = t, c1 = t + 256;
  bool m0 = pb[c0] != 0, m1 = pb[c1] != 0;
  if (type == 1) { m0 = m0 || (c0 > q); m1 = m1 || (c1 > q); }
  const float v0 = m0 ? -1e9f : bf2f(p[c0]) * 0.125f;
  const float v1 = m1 ? -1e9f : bf2f(p[c1]) * 0.125f;
  red[t] = fmaxf(v0, v1);
  __syncthreads();
  for (int s = 128; s > 0; s >>= 1) { if (t < s) red[t] = fmaxf(red[t], red[t + s]); __syncthreads(); }
  const float mx = red[0];
  __syncthreads();
  const float e0 = expf(v0 - mx), e1 = expf(v1 - mx);
  red[t] = e0 + e1;
  __syncthreads();
  for (int s = 128; s > 0; s >>= 1) { if (t < s) red[t] += red[t + s]; __syncthreads(); }
  const float inv = 1.f / red[0];
  p[c0] = f2bf(e0 * inv);
  p[c1] = f2bf(e1 * inv);
}

// out = LN(x + y), torch-style: unbiased std (ddof=1), divide by (std + eps).
// x,y,out bf16; g,b fp32. May be called with out == x (in-place).
__global__ __launch_bounds__(256)
void add_ln(const u16* x, const u16* y, const float* __restrict__ g,
            const float* __restrict__ bb, u16* out)
{
  const int row = blockIdx.x;
  const u16* xr = x + (size_t)row * Dm;
  const u16* yr = y + (size_t)row * Dm;
  u16* orow = out + (size_t)row * Dm;
  const int t = threadIdx.x;
  __shared__ float red[256];
  const float z0 = bf2f(xr[t]) + bf2f(yr[t]);
  const float z1 = bf2f(xr[t + 256]) + bf2f(yr[t + 256]);
  red[t] = z0 + z1;
  __syncthreads();
  for (int s = 128; s > 0; s >>= 1) { if (t < s) red[t] += red[t + s]; __syncthreads(); }
  const float mean = red[0] * (1.f / 512.f);
  __syncthreads();
  const float d0 = z0 - mean, d1 = z1 - mean;
  red[t] = d0 * d0 + d1 * d1;
  __syncthreads();
  for (int s = 128; s > 0; s >>= 1) { if (t < s) red[t] += red[t + s]; __syncthreads(); }
  const float stdv = sqrtf(red[0] * (1.f / 511.f));
  const float inv = 1.f / (stdv + 1e-6f);
  orow[t]       = f2bf(g[t]       * d0 * inv + bb[t]);
  orow[t + 256] = f2bf(g[t + 256] * d1 * inv + bb[t + 256]);
}

// bf16 -> fp32 final output
__global__ __launch_bounds__(256)
void store_f32(const u16* __restrict__ in, float* __restrict__ out, int n)
{
  int i = blockIdx.x * 256 + threadIdx.x;
  if (i < n) out[i] = bf2f(in[i]);
}

extern "C" void kernel_launch(void* const* d_in, const int* in_sizes, int n_in,
                              void* d_out, int out_size, void* d_ws, size_t ws_size,
                              hipStream_t stream)
{
  (void)in_sizes; (void)n_in; (void)out_size;
  const float* enc_in   = (const float*)d_in[0];
  const float* dec_in   = (const float*)d_in[1];
  const float* emb_w    = (const float*)d_in[2];
  const float* emb_b    = (const float*)d_in[3];
  const float* pos      = (const float*)d_in[4];
  const float* e_qkv_w  = (const float*)d_in[5];
  const float* e_qkv_b  = (const float*)d_in[6];
  const float* e_pw     = (const float*)d_in[7];
  const float* e_pb     = (const float*)d_in[8];
  const float* e_ln1    = (const float*)d_in[9];
  const float* e_w1     = (const float*)d_in[10];
  const float* e_b1     = (const float*)d_in[11];
  const float* e_w2     = (const float*)d_in[12];
  const float* e_b2     = (const float*)d_in[13];
  const float* e_ln2    = (const float*)d_in[14];
  const float* ds_qkv_w = (const float*)d_in[15];
  const float* ds_qkv_b = (const float*)d_in[16];
  const float* ds_pw    = (const float*)d_in[17];
  const float* ds_pb    = (const float*)d_in[18];
  const float* d_ln1    = (const float*)d_in[19];
  const float* dc_qkv_w = (const float*)d_in[20];
  const float* dc_qkv_b = (const float*)d_in[21];
  const float* dc_pw    = (const float*)d_in[22];
  const float* dc_pb    = (const float*)d_in[23];
  const float* d_ln2    = (const float*)d_in[24];
  const float* d_w1     = (const float*)d_in[25];
  const float* d_b1     = (const float*)d_in[26];
  const float* d_w2     = (const float*)d_in[27];
  const float* d_b2     = (const float*)d_in[28];
  const float* d_ln3    = (const float*)d_in[29];

  // workspace layout (bf16 elems). sc (8*EL) region also hosts hff (4*EL) and
  // the per-layer converted FFN weights (disjoint liveness: attention vs FFN).
  u16* ws  = (u16*)d_ws;
  u16* enc = ws;             // EL
  u16* dec = ws + EL;        // EL
  u16* qb  = ws + 2 * EL;    // EL  [B,H,S,DK]
  u16* kb  = ws + 3 * EL;    // EL  [B,H,S,DK]
  u16* vT  = ws + 4 * EL;    // EL  [B,H,DK,S]
  u16* ctx = ws + 5 * EL;    // EL  [B,S,H*DK]
  u16* t1  = ws + 6 * EL;    // EL
  u16* sc  = ws + 7 * EL;    // 8*EL [B,H,S,S]
  u16* hff = ws + 7 * EL;    // 4*EL [B,S,Dff]  (overlaps sc)
  u16* wf1 = ws + 11 * EL;            // 4 MAT: current layer w1 (bf16)
  u16* wf2 = ws + 11 * EL + EL / 2;   // 4 MAT: current layer w2 (bf16)
  u16* wT  = ws + 15 * EL;   // 6*EL = 48 transposed bf16 512x512 matrices
  unsigned char* padE = (unsigned char*)(ws + 21 * EL);
  unsigned char* padD = padE + TOK;
  if (ws_size < 21 * EL * 2 + 2 * TOK) return;  // proven to fit in round 1

  // --- one-time weight transposes (fp32 [K,N] -> bf16 [N,K])
  dim3 tb(32, 8);
  transpose512<<<dim3(16, 16, 12), tb, 0, stream>>>(e_qkv_w,  wT);              // [0..11]
  transpose512<<<dim3(16, 16, 12), tb, 0, stream>>>(ds_qkv_w, wT + 12 * MAT);   // [12..23]
  transpose512<<<dim3(16, 16, 12), tb, 0, stream>>>(dc_qkv_w, wT + 24 * MAT);   // [24..35]
  transpose512<<<dim3(16, 16, 4),  tb, 0, stream>>>(e_pw,     wT + 36 * MAT);   // [36..39]
  transpose512<<<dim3(16, 16, 4),  tb, 0, stream>>>(ds_pw,    wT + 40 * MAT);   // [40..43]
  transpose512<<<dim3(16, 16, 4),  tb, 0, stream>>>(dc_pw,    wT + 44 * MAT);   // [44..47]

  // --- embedding + positional encoding, pad masks
  embed_k<<<TOK, 256, 0, stream>>>(enc_in, emb_w, emb_b, pos, enc);
  embed_k<<<TOK, 256, 0, stream>>>(dec_in, emb_w, emb_b, pos, dec);
  pad_k<<<TOK / 256, 256, 0, stream>>>(enc_in, padE);
  pad_k<<<TOK / 256, 256, 0, stream>>>(dec_in, padD);

  auto gemm = [&](const u16* A, const u16* Bt, const float* bias, u16* C,
                  int M, int N, int K, int lda, long long sA, int ldb, long long sB,
                  int ldc, long long sC, int nb, int cmode, int relu) {
    gemm_nt<<<dim3(N / 64, M / 64, nb), 256, 0, stream>>>(
        A, Bt, bias, C, K, lda, sA, ldb, sB, ldc, sC, cmode, relu);
  };

  // full MHA sublayer: x = LN(x + proj(attn(q(x), k(kv), v(kv))))
  auto attention = [&](const u16* qsrc, const u16* kvsrc, const u16* wq3, const float* b3,
                       const u16* pwT, const float* pb, const float* ln,
                       const unsigned char* pad, int mtype, u16* x) {
    gemm(qsrc,  wq3,           b3,        qb, 512, 512, 512, 512, 262144, 512, 0, 0, 0, 8, 1, 0);
    gemm(kvsrc, wq3 + MAT,     b3 + 512,  kb, 512, 512, 512, 512, 262144, 512, 0, 0, 0, 8, 1, 0);
    gemm(kvsrc, wq3 + 2 * MAT, b3 + 1024, vT, 512, 512, 512, 512, 262144, 512, 0, 0, 0, 8, 2, 0);
    // scores[b,h] = Q K^T  (NT), batched over 64 (b,h)
    gemm(qb, kb, nullptr, sc, 512, 512, 64, 64, 32768, 64, 32768, 512, 262144, 64, 0, 0);
    softmax_mask<<<Bz * Hh * Sq, 256, 0, stream>>>(sc, pad, mtype);
    // ctx[b,h] = P V  (NT against vT), scatter into [B,S,H*DK]
    gemm(sc, vT, nullptr, ctx, 512, 64, 512, 512, 262144, 512, 32768, 0, 0, 64, 3, 0);
    gemm(ctx, pwT, pb, t1, 4096, 512, 512, 512, 0, 512, 0, 512, 0, 1, 0, 0);
    add_ln<<<TOK, 256, 0, stream>>>(x, t1, ln, ln + 512, x);
  };

  auto ffn = [&](u16* x, const float* w1, const float* b1, const float* w2,
                 const float* b2, const float* ln) {
    convert_f2b<<<(int)(Dff * Dm / 256), 256, 0, stream>>>(w1, wf1, Dff * Dm);
    convert_f2b<<<(int)(Dff * Dm / 256), 256, 0, stream>>>(w2, wf2, Dff * Dm);
    gemm(x,   wf1, b1, hff, 4096, 2048, 512,  512,  0, 512,  0, 2048, 0, 1, 0, 1);
    gemm(hff, wf2, b2, t1,  4096, 512,  2048, 2048, 0, 2048, 0, 512,  0, 1, 0, 0);
    add_ln<<<TOK, 256, 0, stream>>>(x, t1, ln, ln + 512, x);
  };

  // --- encoder stack
  for (int i = 0; i < NL; ++i) {
    attention(enc, enc, wT + (size_t)(i * 3) * MAT, e_qkv_b + i * 3 * 512,
              wT + (size_t)(36 + i) * MAT, e_pb + i * 512, e_ln1 + i * 1024, padE, 0, enc);
    ffn(enc, e_w1 + (size_t)i * Dff * Dm, e_b1 + i * Dff,
        e_w2 + (size_t)i * Dm * Dff, e_b2 + i * Dm, e_ln2 + i * 1024);
  }

  // --- decoder stack
  for (int i = 0; i < NL; ++i) {
    attention(dec, dec, wT + (size_t)(12 + i * 3) * MAT, ds_qkv_b + i * 3 * 512,
              wT + (size_t)(40 + i) * MAT, ds_pb + i * 512, d_ln1 + i * 1024, padD, 1, dec);
    attention(dec, enc, wT + (size_t)(24 + i * 3) * MAT, dc_qkv_b + i * 3 * 512,
              wT + (size_t)(44 + i) * MAT, dc_pb + i * 512, d_ln2 + i * 1024, padE, 2, dec);
    ffn(dec, d_w1 + (size_t)i * Dff * Dm, d_b1 + i * Dff,
        d_w2 + (size_t)i * Dm * Dff, d_b2 + i * Dm, d_ln3 + i * 1024);
  }

  store_f32<<<(int)((EL + 255) / 256), 256, 0, stream>>>(dec, (float*)d_out, (int)EL);
}

// Round 3
// 2392.466 us; speedup vs baseline: 1.5790x; 1.5790x over previous
//
#include <hip/hip_runtime.h>
#include <cstdint>
#include <cstddef>

typedef unsigned short u16;
typedef __bf16 bf16x8 __attribute__((ext_vector_type(8)));
typedef float f32x4 __attribute__((ext_vector_type(4)));

constexpr int Bz = 8, Sq = 512, Hh = 8, DKd = 64, Dm = 512, Dff = 2048, NL = 4;
constexpr int TOK = Bz * Sq;               // 4096 tokens
constexpr size_t MAT = (size_t)512 * 512;  // 262144 elems per 512x512 matrix
constexpr size_t EL  = (size_t)TOK * Dm;   // 2097152 elems per activation tensor

__device__ __forceinline__ float bf2f(u16 u) {
  union { uint32_t i; float f; } v; v.i = (uint32_t)u << 16; return v.f;
}
__device__ __forceinline__ u16 f2bf(float f) {
  union { float f; uint32_t i; } v; v.f = f;
  uint32_t i = v.i;
  i += 0x7fffu + ((i >> 16) & 1u);   // round-to-nearest-even
  return (u16)(i >> 16);
}

// async global -> LDS, 16B per lane (global_load_lds_dwordx4)
__device__ __forceinline__ void gload16(const u16* g, u16* l) {
  __builtin_amdgcn_global_load_lds(
      (const __attribute__((address_space(1))) unsigned int*)g,
      (__attribute__((address_space(3))) unsigned int*)l, 16, 0, 0);
}

// ---------------------------------------------------------------------------
// Tiled NT GEMM (m97 structure): C[M,N] = A[M,K] @ Bt[N,K]^T (+bias) (+relu)
// 256 threads = 4 waves in 2x2; block tile BM x BN, BK=32; LDS staging via
// global_load_lds width=16; ds_read_b128 frags; MFMA 16x16x32 bf16.
// cmode 0: plain      off = bz*sC + row*ldc + col
// cmode 3: ctx        off = (bz>>3)*262144 + row*512 + (bz&7)*64 + col   [B,S,H*DK]
// cmode 4: qkv split  colx = colofs+col; sec=colx>>9 (0:Q 1:K 2:V); C is qb,
//                     K at C+EL, V^T at C+2*EL ([B,H,DK,S])
// Requires M%BM==0, N%BN==0, K%32==0, lda/ldb %8==0.
// ---------------------------------------------------------------------------
template<int BM, int BN>
__global__ __launch_bounds__(256)
void gemm_tile(const u16* __restrict__ A, const u16* __restrict__ Bt,
               const float* __restrict__ bias, u16* __restrict__ C,
               int K, int lda, long long sA, int ldb, long long sB,
               int ldc, long long sC, int cmode, int relu, int colofs)
{
  constexpr int HM = BM / 2, HN = BN / 2, MI = HM / 16, NI = HN / 16;
  __shared__ __align__(16) u16 As[BM * 32];
  __shared__ __align__(16) u16 Bs[BN * 32];
  const int bz = blockIdx.z;
  const u16* Ab = A + (size_t)bz * (size_t)sA + (size_t)(blockIdx.y * BM) * lda;
  const u16* Bb = Bt + (size_t)bz * (size_t)sB + (size_t)(blockIdx.x * BN) * ldb;
  const int tid  = threadIdx.x;
  const int lane = tid & 63;
  const int wid  = tid >> 6;
  const int l15  = lane & 15;
  const int quad = lane >> 4;
  const int wm   = wid >> 1, wn = wid & 1;

  f32x4 acc[MI][NI] = {};

  for (int k0 = 0; k0 < K; k0 += 32) {
#pragma unroll
    for (int i = 0; i < BM / 64; ++i) {
      const int s = tid + i * 256;                       // slot: row = s>>2, chunk = s&3
      gload16(Ab + (size_t)(s >> 2) * lda + k0 + (s & 3) * 8, As + s * 8);
    }
#pragma unroll
    for (int i = 0; i < BN / 64; ++i) {
      const int s = tid + i * 256;
      gload16(Bb + (size_t)(s >> 2) * ldb + k0 + (s & 3) * 8, Bs + s * 8);
    }
    __syncthreads();
    bf16x8 af[MI], bfr[NI];
#pragma unroll
    for (int mi = 0; mi < MI; ++mi)
      af[mi] = *(const bf16x8*)(As + (wm * HM + mi * 16 + l15) * 32 + quad * 8);
#pragma unroll
    for (int ni = 0; ni < NI; ++ni)
      bfr[ni] = *(const bf16x8*)(Bs + (wn * HN + ni * 16 + l15) * 32 + quad * 8);
#pragma unroll
    for (int mi = 0; mi < MI; ++mi)
#pragma unroll
      for (int ni = 0; ni < NI; ++ni)
        acc[mi][ni] = __builtin_amdgcn_mfma_f32_16x16x32_bf16(af[mi], bfr[ni], acc[mi][ni], 0, 0, 0);
    __syncthreads();
  }

  const int rblk = blockIdx.y * BM + wm * HM + quad * 4;
  const int cblk = blockIdx.x * BN + wn * HN;
#pragma unroll
  for (int ni = 0; ni < NI; ++ni) {
    const int col  = cblk + ni * 16 + l15;
    const int colx = colofs + col;
    const float bv = bias ? bias[colx] : 0.f;
#pragma unroll
    for (int mi = 0; mi < MI; ++mi) {
#pragma unroll
      for (int r = 0; r < 4; ++r) {
        float v = acc[mi][ni][r] + bv;
        if (relu) v = fmaxf(v, 0.f);
        const int grow = rblk + mi * 16 + r;
        size_t off;
        if (cmode == 0) {
          off = (size_t)bz * (size_t)sC + (size_t)grow * ldc + col;
        } else if (cmode == 3) {
          off = (size_t)(bz >> 3) * 262144 + (size_t)grow * 512 + (size_t)(bz & 7) * 64 + col;
        } else {  // 4: qkv scatter
          const int sec = colx >> 9, n = colx & 511, h = n >> 6, d = n & 63;
          const int b = grow >> 9, s = grow & 511;
          if (sec < 2) off = (size_t)sec * EL + (size_t)b * 262144 + (size_t)h * 32768 + (size_t)s * 64 + d;
          else         off = 2 * EL + (size_t)b * 262144 + (size_t)h * 32768 + (size_t)d * 512 + s;
        }
        C[off] = f2bf(v);
      }
    }
  }
}

// 512x512 transpose, fp32 in -> bf16 out, batched over blockIdx.z
__global__ __launch_bounds__(256)
void transpose512(const float* __restrict__ in, u16* __restrict__ out)
{
  __shared__ float tile[32][33];
  const size_t base = (size_t)blockIdx.z * MAT;
  int x = blockIdx.x * 32 + threadIdx.x;
  int y = blockIdx.y * 32 + threadIdx.y;
#pragma unroll
  for (int i = 0; i < 32; i += 8)
    tile[threadIdx.y + i][threadIdx.x] = in[base + (size_t)(y + i) * 512 + x];
  __syncthreads();
  x = blockIdx.y * 32 + threadIdx.x;
  y = blockIdx.x * 32 + threadIdx.y;
#pragma unroll
  for (int i = 0; i < 32; i += 8)
    out[base + (size_t)(y + i) * 512 + x] = f2bf(tile[threadIdx.x][threadIdx.y + i]);
}

// flat fp32 -> bf16 convert
__global__ __launch_bounds__(256)
void convert_f2b(const float* __restrict__ in, u16* __restrict__ out, int n)
{
  int i = blockIdx.x * 256 + threadIdx.x;
  if (i < n) out[i] = f2bf(in[i]);
}

// out[b,s,:] = concat(x[b,s,:], x@emb_w^T + emb_b) + pos_table[s+1]  (fp32 in, bf16 out)
__global__ __launch_bounds__(256)
void embed_k(const float* __restrict__ x, const float* __restrict__ ew,
             const float* __restrict__ eb, const float* __restrict__ pos,
             u16* __restrict__ out)
{
  const int rs = blockIdx.x;          // b*512 + s
  const int s  = rs & 511;
  __shared__ float xr[32];
  const int t = threadIdx.x;
  if (t < 32) xr[t] = x[(size_t)rs * 32 + t];
  __syncthreads();
#pragma unroll
  for (int rep = 0; rep < 2; ++rep) {
    const int c = t + rep * 256;
    float v;
    if (c < 32) {
      v = xr[c];
    } else {
      const float* w = ew + (size_t)(c - 32) * 32;
      float acc = eb[c - 32];
#pragma unroll
      for (int f = 0; f < 32; ++f) acc += xr[f] * w[f];
      v = acc;
    }
    v += pos[(size_t)(s + 1) * 512 + c];
    out[(size_t)rs * 512 + c] = f2bf(v);
  }
}

// pad[b,s] = (sum_f x[b,s,f] <= -9999)  (fp32 in)
__global__ __launch_bounds__(256)
void pad_k(const float* __restrict__ x, unsigned char* __restrict__ pad)
{
  int r = blockIdx.x * 256 + threadIdx.x;
  if (r < TOK) {
    float s = 0.f;
    for (int f = 0; f < 32; ++f) s += x[(size_t)r * 32 + f];
    pad[r] = (s <= -9999.f) ? 1 : 0;
  }
}

// in-place masked, scaled softmax over rows of 512 (bf16 scores).
// row = (b*H + h)*512 + q.  type: 0/2 = pad-only, 1 = pad | causal(col>q)
__global__ __launch_bounds__(256)
void softmax_mask(u16* sc, const unsigned char* __restrict__ pad, int type)
{
  const int row = blockIdx.x;
  const int q = row & 511;
  const int b = row >> 12;            // H*S = 4096 rows per batch
  u16* p = sc + (size_t)row * 512;
  const unsigned char* pb = pad + b * 512;
  const int t = threadIdx.x;
  __shared__ float red[256];
  const int c0 = t, c1 = t + 256;
  bool m0 = pb[c0] != 0, m1 = pb[c1] != 0;
  if (type == 1) { m0 = m0 || (c0 > q); m1 = m1 || (c1 > q); }
  const float v0 = m0 ? -1e9f : bf2f(p[c0]) * 0.125f;
  const float v1 = m1 ? -1e9f : bf2f(p[c1]) * 0.125f;
  red[t] = fmaxf(v0, v1);
  __syncthreads();
  for (int s = 128; s > 0; s >>= 1) { if (t < s) red[t] = fmaxf(red[t], red[t + s]); __syncthreads(); }
  const float mx = red[0];
  __syncthreads();
  const float e0 = expf(v0 - mx), e1 = expf(v1 - mx);
  red[t] = e0 + e1;
  __syncthreads();
  for (int s = 128; s > 0; s >>= 1) { if (t < s) red[t] += red[t + s]; __syncthreads(); }
  const float inv = 1.f / red[0];
  p[c0] = f2bf(e0 * inv);
  p[c1] = f2bf(e1 * inv);
}

// out = LN(x + y), torch-style: unbiased std (ddof=1), divide by (std + eps).
// x,y,out bf16; g,b fp32. May be called with out == x (in-place).
__global__ __launch_bounds__(256)
void add_ln(const u16* x, const u16* y, const float* __restrict__ g,
            const float* __restrict__ bb, u16* out)
{
  const int row = blockIdx.x;
  const u16* xr = x + (size_t)row * Dm;
  const u16* yr = y + (size_t)row * Dm;
  u16* orow = out + (size_t)row * Dm;
  const int t = threadIdx.x;
  __shared__ float red[256];
  const float z0 = bf2f(xr[t]) + bf2f(yr[t]);
  const float z1 = bf2f(xr[t + 256]) + bf2f(yr[t + 256]);
  red[t] = z0 + z1;
  __syncthreads();
  for (int s = 128; s > 0; s >>= 1) { if (t < s) red[t] += red[t + s]; __syncthreads(); }
  const float mean = red[0] * (1.f / 512.f);
  __syncthreads();
  const float d0 = z0 - mean, d1 = z1 - mean;
  red[t] = d0 * d0 + d1 * d1;
  __syncthreads();
  for (int s = 128; s > 0; s >>= 1) { if (t < s) red[t] += red[t + s]; __syncthreads(); }
  const float stdv = sqrtf(red[0] * (1.f / 511.f));
  const float inv = 1.f / (stdv + 1e-6f);
  orow[t]       = f2bf(g[t]       * d0 * inv + bb[t]);
  orow[t + 256] = f2bf(g[t + 256] * d1 * inv + bb[t + 256]);
}

// bf16 -> fp32 final output
__global__ __launch_bounds__(256)
void store_f32(const u16* __restrict__ in, float* __restrict__ out, int n)
{
  int i = blockIdx.x * 256 + threadIdx.x;
  if (i < n) out[i] = bf2f(in[i]);
}

extern "C" void kernel_launch(void* const* d_in, const int* in_sizes, int n_in,
                              void* d_out, int out_size, void* d_ws, size_t ws_size,
                              hipStream_t stream)
{
  (void)in_sizes; (void)n_in; (void)out_size;
  const float* enc_in   = (const float*)d_in[0];
  const float* dec_in   = (const float*)d_in[1];
  const float* emb_w    = (const float*)d_in[2];
  const float* emb_b    = (const float*)d_in[3];
  const float* pos      = (const float*)d_in[4];
  const float* e_qkv_w  = (const float*)d_in[5];
  const float* e_qkv_b  = (const float*)d_in[6];
  const float* e_pw     = (const float*)d_in[7];
  const float* e_pb     = (const float*)d_in[8];
  const float* e_ln1    = (const float*)d_in[9];
  const float* e_w1     = (const float*)d_in[10];
  const float* e_b1     = (const float*)d_in[11];
  const float* e_w2     = (const float*)d_in[12];
  const float* e_b2     = (const float*)d_in[13];
  const float* e_ln2    = (const float*)d_in[14];
  const float* ds_qkv_w = (const float*)d_in[15];
  const float* ds_qkv_b = (const float*)d_in[16];
  const float* ds_pw    = (const float*)d_in[17];
  const float* ds_pb    = (const float*)d_in[18];
  const float* d_ln1    = (const float*)d_in[19];
  const float* dc_qkv_w = (const float*)d_in[20];
  const float* dc_qkv_b = (const float*)d_in[21];
  const float* dc_pw    = (const float*)d_in[22];
  const float* dc_pb    = (const float*)d_in[23];
  const float* d_ln2    = (const float*)d_in[24];
  const float* d_w1     = (const float*)d_in[25];
  const float* d_b1     = (const float*)d_in[26];
  const float* d_w2     = (const float*)d_in[27];
  const float* d_b2     = (const float*)d_in[28];
  const float* d_ln3    = (const float*)d_in[29];

  // workspace layout (bf16 elems). sc (8*EL: 7EL..15EL) hosts hff (7..11EL) and
  // per-layer FFN weights wf1/wf2 (11..12EL) — disjoint liveness (attn vs FFN).
  u16* ws  = (u16*)d_ws;
  u16* enc = ws;             // EL
  u16* dec = ws + EL;        // EL
  u16* qb  = ws + 2 * EL;    // EL  [B,H,S,DK]   (K at +EL, V^T at +2*EL: must stay consecutive)
  u16* kb  = ws + 3 * EL;    // EL  [B,H,S,DK]
  u16* vT  = ws + 4 * EL;    // EL  [B,H,DK,S]
  u16* ctx = ws + 5 * EL;    // EL  [B,S,H*DK]
  u16* t1  = ws + 6 * EL;    // EL
  u16* sc  = ws + 7 * EL;    // 8*EL [B,H,S,S]
  u16* hff = ws + 7 * EL;    // 4*EL [B,S,Dff]  (overlaps sc)
  u16* wf1 = ws + 11 * EL;            // 4 MAT: current layer w1 (bf16)
  u16* wf2 = ws + 11 * EL + EL / 2;   // 4 MAT: current layer w2 (bf16)
  u16* wT  = ws + 15 * EL;   // 6*EL = 48 transposed bf16 512x512 matrices
  unsigned char* padE = (unsigned char*)(ws + 21 * EL);
  unsigned char* padD = padE + TOK;
  if (ws_size < 21 * EL * 2 + 2 * TOK) return;

  // --- one-time weight transposes (fp32 [K,N] -> bf16 [N,K]); per layer the
  // three qkv matrices land contiguously => fused [1536,512] NT weight.
  dim3 tb(32, 8);
  transpose512<<<dim3(16, 16, 12), tb, 0, stream>>>(e_qkv_w,  wT);              // [0..11]
  transpose512<<<dim3(16, 16, 12), tb, 0, stream>>>(ds_qkv_w, wT + 12 * MAT);   // [12..23]
  transpose512<<<dim3(16, 16, 12), tb, 0, stream>>>(dc_qkv_w, wT + 24 * MAT);   // [24..35]
  transpose512<<<dim3(16, 16, 4),  tb, 0, stream>>>(e_pw,     wT + 36 * MAT);   // [36..39]
  transpose512<<<dim3(16, 16, 4),  tb, 0, stream>>>(ds_pw,    wT + 40 * MAT);   // [40..43]
  transpose512<<<dim3(16, 16, 4),  tb, 0, stream>>>(dc_pw,    wT + 44 * MAT);   // [44..47]

  embed_k<<<TOK, 256, 0, stream>>>(enc_in, emb_w, emb_b, pos, enc);
  embed_k<<<TOK, 256, 0, stream>>>(dec_in, emb_w, emb_b, pos, dec);
  pad_k<<<TOK / 256, 256, 0, stream>>>(enc_in, padE);
  pad_k<<<TOK / 256, 256, 0, stream>>>(dec_in, padD);

  // full MHA sublayer: x = LN(x + proj(attn(q(x), k(kv), v(kv))))
  auto attention = [&](const u16* qsrc, const u16* kvsrc, const u16* wq3, const float* b3,
                       const u16* pwT, const float* pb, const float* ln,
                       const unsigned char* pad, int mtype, u16* x) {
    if (qsrc == kvsrc) {
      // fused QKV: [4096,512] x [1536,512]^T, scatter into qb/kb/vT
      gemm_tile<128, 128><<<dim3(12, 32, 1), 256, 0, stream>>>(
          qsrc, wq3, b3, qb, 512, 512, 0, 512, 0, 0, 0, 4, 0, 0);
    } else {
      gemm_tile<64, 128><<<dim3(4, 64, 1), 256, 0, stream>>>(
          qsrc, wq3, b3, qb, 512, 512, 0, 512, 0, 0, 0, 4, 0, 0);
      gemm_tile<128, 128><<<dim3(8, 32, 1), 256, 0, stream>>>(
          kvsrc, wq3 + MAT, b3, qb, 512, 512, 0, 512, 0, 0, 0, 4, 0, 512);
    }
    // scores[b,h] = Q K^T : M=N=512, K=64, batched over 64
    gemm_tile<128, 128><<<dim3(4, 4, 64), 256, 0, stream>>>(
        qb, kb, nullptr, sc, 64, 64, 32768, 64, 32768, 512, 262144, 0, 0, 0);
    softmax_mask<<<Bz * Hh * Sq, 256, 0, stream>>>(sc, pad, mtype);
    // ctx[b,h] = P V : M=512, N=64, K=512, batched over 64, scatter to [B,S,H*DK]
    gemm_tile<128, 64><<<dim3(1, 4, 64), 256, 0, stream>>>(
        sc, vT, nullptr, ctx, 512, 512, 262144, 512, 32768, 0, 0, 3, 0, 0);
    // output projection [4096,512] x [512,512]^T
    gemm_tile<64, 128><<<dim3(4, 64, 1), 256, 0, stream>>>(
        ctx, pwT, pb, t1, 512, 512, 0, 512, 0, 512, 0, 0, 0, 0);
    add_ln<<<TOK, 256, 0, stream>>>(x, t1, ln, ln + 512, x);
  };

  auto ffn = [&](u16* x, const float* w1, const float* b1, const float* w2,
                 const float* b2, const float* ln) {
    convert_f2b<<<4096, 256, 0, stream>>>(w1, wf1, Dff * Dm);
    convert_f2b<<<4096, 256, 0, stream>>>(w2, wf2, Dff * Dm);
    gemm_tile<128, 128><<<dim3(16, 32, 1), 256, 0, stream>>>(
        x, wf1, b1, hff, 512, 512, 0, 512, 0, 2048, 0, 0, 1, 0);
    gemm_tile<64, 128><<<dim3(4, 64, 1), 256, 0, stream>>>(
        hff, wf2, b2, t1, 2048, 2048, 0, 2048, 0, 512, 0, 0, 0, 0);
    add_ln<<<TOK, 256, 0, stream>>>(x, t1, ln, ln + 512, x);
  };

  for (int i = 0; i < NL; ++i) {
    attention(enc, enc, wT + (size_t)(i * 3) * MAT, e_qkv_b + i * 3 * 512,
              wT + (size_t)(36 + i) * MAT, e_pb + i * 512, e_ln1 + i * 1024, padE, 0, enc);
    ffn(enc, e_w1 + (size_t)i * Dff * Dm, e_b1 + i * Dff,
        e_w2 + (size_t)i * Dm * Dff, e_b2 + i * Dm, e_ln2 + i * 1024);
  }

  for (int i = 0; i < NL; ++i) {
    attention(dec, dec, wT + (size_t)(12 + i * 3) * MAT, ds_qkv_b + i * 3 * 512,
              wT + (size_t)(40 + i) * MAT, ds_pb + i * 512, d_ln1 + i * 1024, padD, 1, dec);
    attention(dec, enc, wT + (size_t)(24 + i * 3) * MAT, dc_qkv_b + i * 3 * 512,
              wT + (size_t)(44 + i) * MAT, dc_pb + i * 512, d_ln2 + i * 1024, padE, 2, dec);
    ffn(dec, d_w1 + (size_t)i * Dff * Dm, d_b1 + i * Dff,
        d_w2 + (size_t)i * Dm * Dff, d_b2 + i * Dm, d_ln3 + i * 1024);
  }

  store_f32<<<(int)((EL + 255) / 256), 256, 0, stream>>>(dec, (float*)d_out, (int)EL);
}

// Round 4
// 2028.351 us; speedup vs baseline: 1.8625x; 1.1795x over previous
//
#include <hip/hip_runtime.h>
#include <cstdint>
#include <cstddef>

typedef unsigned short u16;
typedef __bf16 bf16x8 __attribute__((ext_vector_type(8)));
typedef float f32x4 __attribute__((ext_vector_type(4)));

constexpr int Bz = 8, Sq = 512, Hh = 8, DKd = 64, Dm = 512, Dff = 2048, NL = 4;
constexpr int TOK = Bz * Sq;               // 4096 tokens
constexpr size_t MAT = (size_t)512 * 512;  // 262144 elems per 512x512 matrix
constexpr size_t EL  = (size_t)TOK * Dm;   // 2097152 elems per activation tensor

__device__ __forceinline__ float bf2f(u16 u) {
  union { uint32_t i; float f; } v; v.i = (uint32_t)u << 16; return v.f;
}
__device__ __forceinline__ u16 f2bf(float f) {
  union { float f; uint32_t i; } v; v.f = f;
  uint32_t i = v.i;
  i += 0x7fffu + ((i >> 16) & 1u);   // round-to-nearest-even
  return (u16)(i >> 16);
}

// async global -> LDS, 16B per lane (global_load_lds_dwordx4)
__device__ __forceinline__ void gload16(const u16* g, u16* l) {
  __builtin_amdgcn_global_load_lds(
      (const __attribute__((address_space(1))) unsigned int*)g,
      (__attribute__((address_space(3))) unsigned int*)l, 16, 0, 0);
}

// ---------------------------------------------------------------------------
// Tiled NT GEMM (m97 structure): C[M,N] = A[M,K] @ Bt[N,K]^T (+bias) (+relu)
// 256 threads = 4 waves in 2x2; block tile BM x BN, BK=32; LDS staging via
// global_load_lds width=16; ds_read_b128 frags; MFMA 16x16x32 bf16.
// cmode 0: plain      off = bz*sC + row*ldc + col
// cmode 3: ctx        off = (bz>>3)*262144 + row*512 + (bz&7)*64 + col   [B,S,H*DK]
// cmode 4: qkv split  colx = colofs+col; sec=colx>>9 (0:Q 1:K 2:V); C is qb,
//                     K at C+EL, V^T at C+2*EL ([B,H,DK,S]); Q scaled by 0.125
// ---------------------------------------------------------------------------
template<int BM, int BN>
__global__ __launch_bounds__(256)
void gemm_tile(const u16* __restrict__ A, const u16* __restrict__ Bt,
               const float* __restrict__ bias, u16* __restrict__ C,
               int K, int lda, long long sA, int ldb, long long sB,
               int ldc, long long sC, int cmode, int relu, int colofs)
{
  constexpr int HM = BM / 2, HN = BN / 2, MI = HM / 16, NI = HN / 16;
  __shared__ __align__(16) u16 As[BM * 32];
  __shared__ __align__(16) u16 Bs[BN * 32];
  const int bz = blockIdx.z;
  const u16* Ab = A + (size_t)bz * (size_t)sA + (size_t)(blockIdx.y * BM) * lda;
  const u16* Bb = Bt + (size_t)bz * (size_t)sB + (size_t)(blockIdx.x * BN) * ldb;
  const int tid  = threadIdx.x;
  const int lane = tid & 63;
  const int wid  = tid >> 6;
  const int l15  = lane & 15;
  const int quad = lane >> 4;
  const int wm   = wid >> 1, wn = wid & 1;

  f32x4 acc[MI][NI] = {};

  for (int k0 = 0; k0 < K; k0 += 32) {
#pragma unroll
    for (int i = 0; i < BM / 64; ++i) {
      const int s = tid + i * 256;                       // slot: row = s>>2, chunk = s&3
      gload16(Ab + (size_t)(s >> 2) * lda + k0 + (s & 3) * 8, As + s * 8);
    }
#pragma unroll
    for (int i = 0; i < BN / 64; ++i) {
      const int s = tid + i * 256;
      gload16(Bb + (size_t)(s >> 2) * ldb + k0 + (s & 3) * 8, Bs + s * 8);
    }
    __syncthreads();
    bf16x8 af[MI], bfr[NI];
#pragma unroll
    for (int mi = 0; mi < MI; ++mi)
      af[mi] = *(const bf16x8*)(As + (wm * HM + mi * 16 + l15) * 32 + quad * 8);
#pragma unroll
    for (int ni = 0; ni < NI; ++ni)
      bfr[ni] = *(const bf16x8*)(Bs + (wn * HN + ni * 16 + l15) * 32 + quad * 8);
#pragma unroll
    for (int mi = 0; mi < MI; ++mi)
#pragma unroll
      for (int ni = 0; ni < NI; ++ni)
        acc[mi][ni] = __builtin_amdgcn_mfma_f32_16x16x32_bf16(af[mi], bfr[ni], acc[mi][ni], 0, 0, 0);
    __syncthreads();
  }

  const int rblk = blockIdx.y * BM + wm * HM + quad * 4;
  const int cblk = blockIdx.x * BN + wn * HN;
#pragma unroll
  for (int ni = 0; ni < NI; ++ni) {
    const int col  = cblk + ni * 16 + l15;
    const int colx = colofs + col;
    const float bv = bias ? bias[colx] : 0.f;
#pragma unroll
    for (int mi = 0; mi < MI; ++mi) {
#pragma unroll
      for (int r = 0; r < 4; ++r) {
        float v = acc[mi][ni][r] + bv;
        if (relu) v = fmaxf(v, 0.f);
        const int grow = rblk + mi * 16 + r;
        size_t off;
        if (cmode == 0) {
          off = (size_t)bz * (size_t)sC + (size_t)grow * ldc + col;
        } else if (cmode == 3) {
          off = (size_t)(bz >> 3) * 262144 + (size_t)grow * 512 + (size_t)(bz & 7) * 64 + col;
        } else {  // 4: qkv scatter; fold 1/sqrt(DK)=0.125 into Q
          const int sec = colx >> 9, n = colx & 511, h = n >> 6, d = n & 63;
          const int b = grow >> 9, s = grow & 511;
          if (sec == 0) v *= 0.125f;
          if (sec < 2) off = (size_t)sec * EL + (size_t)b * 262144 + (size_t)h * 32768 + (size_t)s * 64 + d;
          else         off = 2 * EL + (size_t)b * 262144 + (size_t)h * 32768 + (size_t)d * 512 + s;
        }
        C[off] = f2bf(v);
      }
    }
  }
}

// 512x512 transpose, fp32 in -> bf16 out, batched over blockIdx.z
__global__ __launch_bounds__(256)
void transpose512(const float* __restrict__ in, u16* __restrict__ out)
{
  __shared__ float tile[32][33];
  const size_t base = (size_t)blockIdx.z * MAT;
  int x = blockIdx.x * 32 + threadIdx.x;
  int y = blockIdx.y * 32 + threadIdx.y;
#pragma unroll
  for (int i = 0; i < 32; i += 8)
    tile[threadIdx.y + i][threadIdx.x] = in[base + (size_t)(y + i) * 512 + x];
  __syncthreads();
  x = blockIdx.y * 32 + threadIdx.x;
  y = blockIdx.x * 32 + threadIdx.y;
#pragma unroll
  for (int i = 0; i < 32; i += 8)
    out[base + (size_t)(y + i) * 512 + x] = f2bf(tile[threadIdx.x][threadIdx.y + i]);
}

// dual fp32 -> bf16 convert, 4 elems per thread from each source (n % 4 == 0)
__global__ __launch_bounds__(256)
void convert2(const float* __restrict__ w1, const float* __restrict__ w2,
              u16* __restrict__ o1, u16* __restrict__ o2, int n)
{
  int i = (blockIdx.x * 256 + threadIdx.x) * 4;
  if (i < n) {
    float4 a = *(const float4*)(w1 + i);
    float4 b = *(const float4*)(w2 + i);
    ushort4 ua = { f2bf(a.x), f2bf(a.y), f2bf(a.z), f2bf(a.w) };
    ushort4 ub = { f2bf(b.x), f2bf(b.y), f2bf(b.z), f2bf(b.w) };
    *(ushort4*)(o1 + i) = ua;
    *(ushort4*)(o2 + i) = ub;
  }
}

// out[b,s,:] = concat(x[b,s,:], x@emb_w^T + emb_b) + pos_table[s+1]  (fp32 in, bf16 out)
__global__ __launch_bounds__(256)
void embed_k(const float* __restrict__ x, const float* __restrict__ ew,
             const float* __restrict__ eb, const float* __restrict__ pos,
             u16* __restrict__ out)
{
  const int rs = blockIdx.x;          // b*512 + s
  const int s  = rs & 511;
  __shared__ float xr[32];
  const int t = threadIdx.x;
  if (t < 32) xr[t] = x[(size_t)rs * 32 + t];
  __syncthreads();
#pragma unroll
  for (int rep = 0; rep < 2; ++rep) {
    const int c = t + rep * 256;
    float v;
    if (c < 32) {
      v = xr[c];
    } else {
      const float* w = ew + (size_t)(c - 32) * 32;
      float acc = eb[c - 32];
#pragma unroll
      for (int f = 0; f < 32; ++f) acc += xr[f] * w[f];
      v = acc;
    }
    v += pos[(size_t)(s + 1) * 512 + c];
    out[(size_t)rs * 512 + c] = f2bf(v);
  }
}

// pad[b,s] = (sum_f x[b,s,f] <= -9999)  (fp32 in)
__global__ __launch_bounds__(256)
void pad_k(const float* __restrict__ x, unsigned char* __restrict__ pad)
{
  int r = blockIdx.x * 256 + threadIdx.x;
  if (r < TOK) {
    float s = 0.f;
    for (int f = 0; f < 32; ++f) s += x[(size_t)r * 32 + f];
    pad[r] = (s <= -9999.f) ? 1 : 0;
  }
}

// wave-per-row masked softmax over rows of 512 (bf16, already scaled).
// 4 rows per 256-thread block; shuffle reductions, no barriers.
// row = (b*H + h)*512 + q.  type: 0/2 = pad-only, 1 = pad | causal(col>q)
__global__ __launch_bounds__(256)
void softmax_mask(u16* sc, const unsigned char* __restrict__ pad, int type)
{
  const int row  = blockIdx.x * 4 + (threadIdx.x >> 6);
  const int lane = threadIdx.x & 63;
  const int q = row & 511;
  const int b = row >> 12;            // H*S = 4096 rows per batch
  u16* p = sc + (size_t)row * 512 + lane * 8;
  const unsigned char* pb = pad + b * 512 + lane * 8;

  uint4 raw = *(const uint4*)p;
  const u16* rh = (const u16*)&raw;
  uint2 mk = *(const uint2*)pb;
  const unsigned char* mb = (const unsigned char*)&mk;
  const int c0 = lane * 8;

  float v[8];
#pragma unroll
  for (int j = 0; j < 8; ++j) {
    bool m = mb[j] != 0;
    if (type == 1) m = m || (c0 + j > q);
    v[j] = m ? -1e9f : bf2f(rh[j]);
  }
  float mx = v[0];
#pragma unroll
  for (int j = 1; j < 8; ++j) mx = fmaxf(mx, v[j]);
#pragma unroll
  for (int off = 32; off > 0; off >>= 1) mx = fmaxf(mx, __shfl_xor(mx, off));
  float sum = 0.f;
#pragma unroll
  for (int j = 0; j < 8; ++j) { v[j] = __expf(v[j] - mx); sum += v[j]; }
#pragma unroll
  for (int off = 32; off > 0; off >>= 1) sum += __shfl_xor(sum, off);
  const float inv = 1.f / sum;
  uint4 outw;
  u16* oh = (u16*)&outw;
#pragma unroll
  for (int j = 0; j < 8; ++j) oh[j] = f2bf(v[j] * inv);
  *(uint4*)p = outw;
}

// wave-per-row LN(x + y), torch-style (ddof=1, /(std+eps)). 4 rows/block.
// x,y,out bf16; g,b fp32. Safe for out == x (wave touches only its row).
__global__ __launch_bounds__(256)
void add_ln(const u16* __restrict__ x, const u16* __restrict__ y,
            const float* __restrict__ g, const float* __restrict__ bb,
            u16* __restrict__ out)
{
  const int row  = blockIdx.x * 4 + (threadIdx.x >> 6);
  const int lane = threadIdx.x & 63;
  const int c0 = lane * 8;
  const size_t base = (size_t)row * Dm + c0;

  uint4 xr = *(const uint4*)(x + base);
  uint4 yr = *(const uint4*)(y + base);
  const u16* xh = (const u16*)&xr;
  const u16* yh = (const u16*)&yr;
  float z[8];
  float s = 0.f;
#pragma unroll
  for (int j = 0; j < 8; ++j) { z[j] = bf2f(xh[j]) + bf2f(yh[j]); s += z[j]; }
#pragma unroll
  for (int off = 32; off > 0; off >>= 1) s += __shfl_xor(s, off);
  const float mean = s * (1.f / 512.f);
  float ss = 0.f;
#pragma unroll
  for (int j = 0; j < 8; ++j) { z[j] -= mean; ss += z[j] * z[j]; }
#pragma unroll
  for (int off = 32; off > 0; off >>= 1) ss += __shfl_xor(ss, off);
  const float stdv = sqrtf(ss * (1.f / 511.f));
  const float inv = 1.f / (stdv + 1e-6f);

  float4 g0 = *(const float4*)(g + c0),  g1 = *(const float4*)(g + c0 + 4);
  float4 b0 = *(const float4*)(bb + c0), b1 = *(const float4*)(bb + c0 + 4);
  const float* gp = (const float*)&g0;  // g0,g1 contiguous? not guaranteed; use arrays
  float gv[8] = { g0.x, g0.y, g0.z, g0.w, g1.x, g1.y, g1.z, g1.w };
  float bv[8] = { b0.x, b0.y, b0.z, b0.w, b1.x, b1.y, b1.z, b1.w };
  (void)gp;
  uint4 ow;
  u16* oh = (u16*)&ow;
#pragma unroll
  for (int j = 0; j < 8; ++j) oh[j] = f2bf(gv[j] * z[j] * inv + bv[j]);
  *(uint4*)(out + base) = ow;
}

// bf16 -> fp32 final output, 8 per thread
__global__ __launch_bounds__(256)
void store_f32(const u16* __restrict__ in, float* __restrict__ out, int n)
{
  int i = (blockIdx.x * 256 + threadIdx.x) * 8;
  if (i < n) {
    uint4 raw = *(const uint4*)(in + i);
    const u16* h = (const u16*)&raw;
    float4 o0 = { bf2f(h[0]), bf2f(h[1]), bf2f(h[2]), bf2f(h[3]) };
    float4 o1 = { bf2f(h[4]), bf2f(h[5]), bf2f(h[6]), bf2f(h[7]) };
    *(float4*)(out + i) = o0;
    *(float4*)(out + i + 4) = o1;
  }
}

extern "C" void kernel_launch(void* const* d_in, const int* in_sizes, int n_in,
                              void* d_out, int out_size, void* d_ws, size_t ws_size,
                              hipStream_t stream)
{
  (void)in_sizes; (void)n_in; (void)out_size;
  const float* enc_in   = (const float*)d_in[0];
  const float* dec_in   = (const float*)d_in[1];
  const float* emb_w    = (const float*)d_in[2];
  const float* emb_b    = (const float*)d_in[3];
  const float* pos      = (const float*)d_in[4];
  const float* e_qkv_w  = (const float*)d_in[5];
  const float* e_qkv_b  = (const float*)d_in[6];
  const float* e_pw     = (const float*)d_in[7];
  const float* e_pb     = (const float*)d_in[8];
  const float* e_ln1    = (const float*)d_in[9];
  const float* e_w1     = (const float*)d_in[10];
  const float* e_b1     = (const float*)d_in[11];
  const float* e_w2     = (const float*)d_in[12];
  const float* e_b2     = (const float*)d_in[13];
  const float* e_ln2    = (const float*)d_in[14];
  const float* ds_qkv_w = (const float*)d_in[15];
  const float* ds_qkv_b = (const float*)d_in[16];
  const float* ds_pw    = (const float*)d_in[17];
  const float* ds_pb    = (const float*)d_in[18];
  const float* d_ln1    = (const float*)d_in[19];
  const float* dc_qkv_w = (const float*)d_in[20];
  const float* dc_qkv_b = (const float*)d_in[21];
  const float* dc_pw    = (const float*)d_in[22];
  const float* dc_pb    = (const float*)d_in[23];
  const float* d_ln2    = (const float*)d_in[24];
  const float* d_w1     = (const float*)d_in[25];
  const float* d_b1     = (const float*)d_in[26];
  const float* d_w2     = (const float*)d_in[27];
  const float* d_b2     = (const float*)d_in[28];
  const float* d_ln3    = (const float*)d_in[29];

  // workspace layout (bf16 elems). sc (8*EL: 7EL..15EL) hosts hff (7..11EL) and
  // per-layer FFN weights wf1/wf2 (11..12EL) — disjoint liveness (attn vs FFN).
  u16* ws  = (u16*)d_ws;
  u16* enc = ws;             // EL
  u16* dec = ws + EL;        // EL
  u16* qb  = ws + 2 * EL;    // EL  [B,H,S,DK]   (K at +EL, V^T at +2*EL: consecutive)
  u16* kb  = ws + 3 * EL;    // EL  [B,H,S,DK]
  u16* vT  = ws + 4 * EL;    // EL  [B,H,DK,S]
  u16* ctx = ws + 5 * EL;    // EL  [B,S,H*DK]
  u16* t1  = ws + 6 * EL;    // EL
  u16* sc  = ws + 7 * EL;    // 8*EL [B,H,S,S]
  u16* hff = ws + 7 * EL;    // 4*EL [B,S,Dff]  (overlaps sc)
  u16* wf1 = ws + 11 * EL;            // 4 MAT: current layer w1 (bf16)
  u16* wf2 = ws + 11 * EL + EL / 2;   // 4 MAT: current layer w2 (bf16)
  u16* wT  = ws + 15 * EL;   // 6*EL = 48 transposed bf16 512x512 matrices
  unsigned char* padE = (unsigned char*)(ws + 21 * EL);
  unsigned char* padD = padE + TOK;
  if (ws_size < 21 * EL * 2 + 2 * TOK) return;

  // --- one-time weight transposes (fp32 [K,N] -> bf16 [N,K]); per layer the
  // three qkv matrices land contiguously => fused [1536,512] NT weight.
  dim3 tb(32, 8);
  transpose512<<<dim3(16, 16, 12), tb, 0, stream>>>(e_qkv_w,  wT);              // [0..11]
  transpose512<<<dim3(16, 16, 12), tb, 0, stream>>>(ds_qkv_w, wT + 12 * MAT);   // [12..23]
  transpose512<<<dim3(16, 16, 12), tb, 0, stream>>>(dc_qkv_w, wT + 24 * MAT);   // [24..35]
  transpose512<<<dim3(16, 16, 4),  tb, 0, stream>>>(e_pw,     wT + 36 * MAT);   // [36..39]
  transpose512<<<dim3(16, 16, 4),  tb, 0, stream>>>(ds_pw,    wT + 40 * MAT);   // [40..43]
  transpose512<<<dim3(16, 16, 4),  tb, 0, stream>>>(dc_pw,    wT + 44 * MAT);   // [44..47]

  embed_k<<<TOK, 256, 0, stream>>>(enc_in, emb_w, emb_b, pos, enc);
  embed_k<<<TOK, 256, 0, stream>>>(dec_in, emb_w, emb_b, pos, dec);
  pad_k<<<TOK / 256, 256, 0, stream>>>(enc_in, padE);
  pad_k<<<TOK / 256, 256, 0, stream>>>(dec_in, padD);

  // full MHA sublayer: x = LN(x + proj(attn(q(x), k(kv), v(kv))))
  auto attention = [&](const u16* qsrc, const u16* kvsrc, const u16* wq3, const float* b3,
                       const u16* pwT, const float* pb, const float* ln,
                       const unsigned char* pad, int mtype, u16* x) {
    if (qsrc == kvsrc) {
      // fused QKV: [4096,512] x [1536,512]^T, scatter into qb/kb/vT
      gemm_tile<128, 128><<<dim3(12, 32, 1), 256, 0, stream>>>(
          qsrc, wq3, b3, qb, 512, 512, 0, 512, 0, 0, 0, 4, 0, 0);
    } else {
      gemm_tile<64, 128><<<dim3(4, 64, 1), 256, 0, stream>>>(
          qsrc, wq3, b3, qb, 512, 512, 0, 512, 0, 0, 0, 4, 0, 0);
      gemm_tile<128, 128><<<dim3(8, 32, 1), 256, 0, stream>>>(
          kvsrc, wq3 + MAT, b3, qb, 512, 512, 0, 512, 0, 0, 0, 4, 0, 512);
    }
    // scores[b,h] = Q K^T : M=N=512, K=64, batched over 64 (Q pre-scaled)
    gemm_tile<128, 128><<<dim3(4, 4, 64), 256, 0, stream>>>(
        qb, kb, nullptr, sc, 64, 64, 32768, 64, 32768, 512, 262144, 0, 0, 0);
    softmax_mask<<<Bz * Hh * Sq / 4, 256, 0, stream>>>(sc, pad, mtype);
    // ctx[b,h] = P V : M=512, N=64, K=512, batched over 64, scatter to [B,S,H*DK]
    gemm_tile<128, 64><<<dim3(1, 4, 64), 256, 0, stream>>>(
        sc, vT, nullptr, ctx, 512, 512, 262144, 512, 32768, 0, 0, 3, 0, 0);
    // output projection [4096,512] x [512,512]^T
    gemm_tile<64, 128><<<dim3(4, 64, 1), 256, 0, stream>>>(
        ctx, pwT, pb, t1, 512, 512, 0, 512, 0, 512, 0, 0, 0, 0);
    add_ln<<<TOK / 4, 256, 0, stream>>>(x, t1, ln, ln + 512, x);
  };

  auto ffn = [&](u16* x, const float* w1, const float* b1, const float* w2,
                 const float* b2, const float* ln) {
    convert2<<<1024, 256, 0, stream>>>(w1, w2, wf1, wf2, Dff * Dm);
    gemm_tile<128, 128><<<dim3(16, 32, 1), 256, 0, stream>>>(
        x, wf1, b1, hff, 512, 512, 0, 512, 0, 2048, 0, 0, 1, 0);
    gemm_tile<64, 128><<<dim3(4, 64, 1), 256, 0, stream>>>(
        hff, wf2, b2, t1, 2048, 2048, 0, 2048, 0, 512, 0, 0, 0, 0);
    add_ln<<<TOK / 4, 256, 0, stream>>>(x, t1, ln, ln + 512, x);
  };

  for (int i = 0; i < NL; ++i) {
    attention(enc, enc, wT + (size_t)(i * 3) * MAT, e_qkv_b + i * 3 * 512,
              wT + (size_t)(36 + i) * MAT, e_pb + i * 512, e_ln1 + i * 1024, padE, 0, enc);
    ffn(enc, e_w1 + (size_t)i * Dff * Dm, e_b1 + i * Dff,
        e_w2 + (size_t)i * Dm * Dff, e_b2 + i * Dm, e_ln2 + i * 1024);
  }

  for (int i = 0; i < NL; ++i) {
    attention(dec, dec, wT + (size_t)(12 + i * 3) * MAT, ds_qkv_b + i * 3 * 512,
              wT + (size_t)(40 + i) * MAT, ds_pb + i * 512, d_ln1 + i * 1024, padD, 1, dec);
    attention(dec, enc, wT + (size_t)(24 + i * 3) * MAT, dc_qkv_b + i * 3 * 512,
              wT + (size_t)(44 + i) * MAT, dc_pb + i * 512, d_ln2 + i * 1024, padE, 2, dec);
    ffn(dec, d_w1 + (size_t)i * Dff * Dm, d_b1 + i * Dff,
        d_w2 + (size_t)i * Dm * Dff, d_b2 + i * Dm, d_ln3 + i * 1024);
  }

  store_f32<<<(int)(EL / 8 / 256), 256, 0, stream>>>(dec, (float*)d_out, (int)EL);
}

// Round 5
// 1489.013 us; speedup vs baseline: 2.5371x; 1.3622x over previous
//
#include <hip/hip_runtime.h>
#include <cstdint>
#include <cstddef>

typedef unsigned short u16;
typedef __bf16 bf16x8 __attribute__((ext_vector_type(8)));
typedef float f32x4 __attribute__((ext_vector_type(4)));

constexpr int Bz = 8, Sq = 512, Hh = 8, DKd = 64, Dm = 512, Dff = 2048, NL = 4;
constexpr int TOK = Bz * Sq;               // 4096 tokens
constexpr size_t MAT = (size_t)512 * 512;  // 262144 elems per 512x512 matrix
constexpr size_t EL  = (size_t)TOK * Dm;   // 2097152 elems per activation tensor

__device__ __forceinline__ float bf2f(u16 u) {
  union { uint32_t i; float f; } v; v.i = (uint32_t)u << 16; return v.f;
}
__device__ __forceinline__ u16 f2bf(float f) {
  union { float f; uint32_t i; } v; v.f = f;
  uint32_t i = v.i;
  i += 0x7fffu + ((i >> 16) & 1u);   // round-to-nearest-even
  return (u16)(i >> 16);
}

// async global -> LDS, 16B per lane (global_load_lds_dwordx4)
__device__ __forceinline__ void gload16(const u16* g, u16* l) {
  __builtin_amdgcn_global_load_lds(
      (const __attribute__((address_space(1))) unsigned int*)g,
      (__attribute__((address_space(3))) unsigned int*)l, 16, 0, 0);
}

// ---------------------------------------------------------------------------
// Tiled NT GEMM: C[M,N] = A[M,K] @ Bt[N,K]^T (+bias fp32) (+relu)
// 256 threads = 4 waves (2x2); BK=32; global_load_lds staging with XOR chunk
// swizzle (c ^= (row>>1)&3) so frag ds_read_b128 is ~2-way bank-safe.
// cmode 0: plain; 3: ctx scatter [B,S,H*DK]; 4: qkv split (Q scaled 0.125,
//          Q->C, K->C+EL [B,H,S,DK], V->C+2EL transposed [B,H,DK,S]).
// ---------------------------------------------------------------------------
template<int BM, int BN>
__global__ __launch_bounds__(256)
void gemm_tile(const u16* __restrict__ A, const u16* __restrict__ Bt,
               const float* __restrict__ bias, u16* __restrict__ C,
               int K, int lda, long long sA, int ldb, long long sB,
               int ldc, long long sC, int cmode, int relu, int colofs)
{
  constexpr int HM = BM / 2, HN = BN / 2, MI = HM / 16, NI = HN / 16;
  __shared__ __align__(16) u16 As[BM * 32];
  __shared__ __align__(16) u16 Bs[BN * 32];
  const int bz = blockIdx.z;
  const u16* Ab = A + (size_t)bz * (size_t)sA + (size_t)(blockIdx.y * BM) * lda;
  const u16* Bb = Bt + (size_t)bz * (size_t)sB + (size_t)(blockIdx.x * BN) * ldb;
  const int tid  = threadIdx.x;
  const int lane = tid & 63;
  const int wid  = tid >> 6;
  const int l15  = lane & 15;
  const int quad = lane >> 4;
  const int wm   = wid >> 1, wn = wid & 1;

  f32x4 acc[MI][NI] = {};

  for (int k0 = 0; k0 < K; k0 += 32) {
#pragma unroll
    for (int i = 0; i < BM / 64; ++i) {
      const int s = tid + i * 256;               // slot: row=s>>2, stored chunk=s&3
      const int c = (s & 3) ^ ((s >> 3) & 3);    // actual data chunk (swizzle)
      gload16(Ab + (size_t)(s >> 2) * lda + k0 + c * 8, As + s * 8);
    }
#pragma unroll
    for (int i = 0; i < BN / 64; ++i) {
      const int s = tid + i * 256;
      const int c = (s & 3) ^ ((s >> 3) & 3);
      gload16(Bb + (size_t)(s >> 2) * ldb + k0 + c * 8, Bs + s * 8);
    }
    __syncthreads();
    bf16x8 af[MI], bfr[NI];
#pragma unroll
    for (int mi = 0; mi < MI; ++mi) {
      const int ra = wm * HM + mi * 16 + l15;
      af[mi] = *(const bf16x8*)(As + ra * 32 + (quad ^ ((ra >> 1) & 3)) * 8);
    }
#pragma unroll
    for (int ni = 0; ni < NI; ++ni) {
      const int rb = wn * HN + ni * 16 + l15;
      bfr[ni] = *(const bf16x8*)(Bs + rb * 32 + (quad ^ ((rb >> 1) & 3)) * 8);
    }
#pragma unroll
    for (int mi = 0; mi < MI; ++mi)
#pragma unroll
      for (int ni = 0; ni < NI; ++ni)
        acc[mi][ni] = __builtin_amdgcn_mfma_f32_16x16x32_bf16(af[mi], bfr[ni], acc[mi][ni], 0, 0, 0);
    __syncthreads();
  }

  const int rblk = blockIdx.y * BM + wm * HM + quad * 4;
  const int cblk = blockIdx.x * BN + wn * HN;
#pragma unroll
  for (int ni = 0; ni < NI; ++ni) {
    const int col  = cblk + ni * 16 + l15;
    const int colx = colofs + col;
    const float bv = bias ? bias[colx] : 0.f;
#pragma unroll
    for (int mi = 0; mi < MI; ++mi) {
#pragma unroll
      for (int r = 0; r < 4; ++r) {
        float v = acc[mi][ni][r] + bv;
        if (relu) v = fmaxf(v, 0.f);
        const int grow = rblk + mi * 16 + r;
        size_t off;
        if (cmode == 0) {
          off = (size_t)bz * (size_t)sC + (size_t)grow * ldc + col;
        } else if (cmode == 3) {
          off = (size_t)(bz >> 3) * 262144 + (size_t)grow * 512 + (size_t)(bz & 7) * 64 + col;
        } else {  // 4: qkv scatter; fold 1/sqrt(DK)=0.125 into Q
          const int sec = colx >> 9, n = colx & 511, h = n >> 6, d = n & 63;
          const int b = grow >> 9, s = grow & 511;
          if (sec == 0) v *= 0.125f;
          if (sec < 2) off = (size_t)sec * EL + (size_t)b * 262144 + (size_t)h * 32768 + (size_t)s * 64 + d;
          else         off = 2 * EL + (size_t)b * 262144 + (size_t)h * 32768 + (size_t)d * 512 + s;
        }
        C[off] = f2bf(v);
      }
    }
  }
}

// ---------------------------------------------------------------------------
// Fused attention: per block = (q-tile of 64 rows, one (b,h)).
// ctx[b,s,h*64+d] = softmax(mask(Q K^T)) V.  Q pre-scaled by 0.125.
// 4 waves, each owns 16 q rows; S[16x512] in regs; K/V chunks (128) staged in
// LDS (XOR-swizzled for bank-safe b128 reads); P via wave-private LDS.
// mtype: 1 = pad|causal, else pad-only.
// ---------------------------------------------------------------------------
__global__ __launch_bounds__(256)
void flash_attn(const u16* __restrict__ q, const u16* __restrict__ k,
                const u16* __restrict__ v, const unsigned char* __restrict__ pad,
                u16* __restrict__ ctx, int mtype)
{
  __shared__ __align__(16) u16 KVs[8192];      // 16 KB: K or V chunk (swizzled)
  __shared__ __align__(16) u16 Pw[4][2048];    // 4 KB per wave: P tile 16x128
  const int bh = blockIdx.y, b = bh >> 3, h = bh & 7;
  const int qt = blockIdx.x;
  const int tid = threadIdx.x, lane = tid & 63, wid = tid >> 6;
  const int l15 = lane & 15, quad = lane >> 4;
  const size_t bho = (size_t)bh * 32768;
  const int qrow = qt * 64 + wid * 16 + l15;       // A-operand row (this lane)
  const int qcd  = qt * 64 + wid * 16 + quad * 4;  // C-layout row base

  // stage pad bytes into LDS (Pw area; P writes happen after softmax)
  unsigned char* Ps = (unsigned char*)&Pw[0][0];
  if (tid < 128) ((uchar4*)Ps)[tid] = ((const uchar4*)(pad + b * 512))[tid];

  bf16x8 aq0 = *(const bf16x8*)(q + bho + (size_t)qrow * 64 + quad * 8);
  bf16x8 aq1 = *(const bf16x8*)(q + bho + (size_t)qrow * 64 + 32 + quad * 8);

  f32x4 S[32];
#pragma unroll
  for (int kc = 0; kc < 4; ++kc) {
    __syncthreads();
#pragma unroll
    for (int i = 0; i < 4; ++i) {             // stage K chunk [128 keys][64]
      const int s = tid + i * 256;
      const int row = s >> 3, c = (s & 7) ^ (row & 7);
      gload16(k + bho + (size_t)(kc * 128 + row) * 64 + c * 8, KVs + s * 8);
    }
    __syncthreads();
#pragma unroll
    for (int t = 0; t < 8; ++t) {
      const int sw = l15 & 7;
      bf16x8 b0 = *(const bf16x8*)(KVs + (t * 16 + l15) * 64 + (quad ^ sw) * 8);
      bf16x8 b1 = *(const bf16x8*)(KVs + (t * 16 + l15) * 64 + ((4 + quad) ^ sw) * 8);
      f32x4 z = {0.f, 0.f, 0.f, 0.f};
      z = __builtin_amdgcn_mfma_f32_16x16x32_bf16(aq0, b0, z, 0, 0, 0);
      S[kc * 8 + t] = __builtin_amdgcn_mfma_f32_16x16x32_bf16(aq1, b1, z, 0, 0, 0);
    }
  }

  // pad-mask bitmask for this lane's 32 columns (col = t*16 + l15)
  unsigned pm = 0u;
#pragma unroll
  for (int t = 0; t < 32; ++t) pm |= (unsigned)(Ps[t * 16 + l15] != 0) << t;

  // masked softmax per q row (reduce across the 16 lanes sharing a row)
  float inv[4];
#pragma unroll
  for (int r = 0; r < 4; ++r) {
    const int qg = qcd + r;
    float mx = -3.0e38f;
#pragma unroll
    for (int t = 0; t < 32; ++t) {
      const int col = t * 16 + l15;
      const bool m = ((pm >> t) & 1u) || (mtype == 1 && col > qg);
      const float val = m ? -1e9f : S[t][r];
      S[t][r] = val;
      mx = fmaxf(mx, val);
    }
#pragma unroll
    for (int o = 8; o > 0; o >>= 1) mx = fmaxf(mx, __shfl_xor(mx, o));
    float sm = 0.f;
#pragma unroll
    for (int t = 0; t < 32; ++t) { const float e = __expf(S[t][r] - mx); S[t][r] = e; sm += e; }
#pragma unroll
    for (int o = 8; o > 0; o >>= 1) sm += __shfl_xor(sm, o);
    inv[r] = 1.f / sm;
  }

  // P V accumulation over 4 key chunks
  f32x4 O[4] = {};
  u16* myP = &Pw[wid][0];
#pragma unroll
  for (int kc = 0; kc < 4; ++kc) {
    __syncthreads();
#pragma unroll
    for (int i = 0; i < 4; ++i) {             // stage V chunk [64 dk][128 keys]
      const int s = tid + i * 256;
      const int row = s >> 4, c = (s & 15) ^ (row & 15);
      gload16(v + bho + (size_t)row * 512 + kc * 128 + c * 8, KVs + s * 8);
    }
    // write this wave's P chunk (wave-private region, no barrier needed)
#pragma unroll
    for (int t = 0; t < 8; ++t)
#pragma unroll
      for (int r = 0; r < 4; ++r) {
        const int rowq = quad * 4 + r;
        const int c = 2 * t + (l15 >> 3);
        myP[rowq * 128 + (c ^ rowq) * 8 + (l15 & 7)] = f2bf(S[kc * 8 + t][r] * inv[r]);
      }
    __syncthreads();
#pragma unroll
    for (int kk = 0; kk < 4; ++kk) {
      bf16x8 ap = *(const bf16x8*)(myP + l15 * 128 + ((kk * 4 + quad) ^ l15) * 8);
#pragma unroll
      for (int ni = 0; ni < 4; ++ni) {
        bf16x8 bv = *(const bf16x8*)(KVs + (ni * 16 + l15) * 128 + ((kk * 4 + quad) ^ l15) * 8);
        O[ni] = __builtin_amdgcn_mfma_f32_16x16x32_bf16(ap, bv, O[ni], 0, 0, 0);
      }
    }
  }

  const int token = b * 512 + qcd;
#pragma unroll
  for (int ni = 0; ni < 4; ++ni)
#pragma unroll
    for (int r = 0; r < 4; ++r)
      ctx[(size_t)(token + r) * 512 + h * 64 + ni * 16 + l15] = f2bf(O[ni][r]);
}

// 512x512 transpose, fp32 in -> bf16 out, batched over blockIdx.z
__global__ __launch_bounds__(256)
void transpose512(const float* __restrict__ in, u16* __restrict__ out)
{
  __shared__ float tile[32][33];
  const size_t base = (size_t)blockIdx.z * MAT;
  int x = blockIdx.x * 32 + threadIdx.x;
  int y = blockIdx.y * 32 + threadIdx.y;
#pragma unroll
  for (int i = 0; i < 32; i += 8)
    tile[threadIdx.y + i][threadIdx.x] = in[base + (size_t)(y + i) * 512 + x];
  __syncthreads();
  x = blockIdx.y * 32 + threadIdx.x;
  y = blockIdx.x * 32 + threadIdx.y;
#pragma unroll
  for (int i = 0; i < 32; i += 8)
    out[base + (size_t)(y + i) * 512 + x] = f2bf(tile[threadIdx.x][threadIdx.y + i]);
}

// dual fp32 -> bf16 convert, 4 elems per thread from each source (n % 4 == 0)
__global__ __launch_bounds__(256)
void convert2(const float* __restrict__ w1, const float* __restrict__ w2,
              u16* __restrict__ o1, u16* __restrict__ o2, int n)
{
  int i = (blockIdx.x * 256 + threadIdx.x) * 4;
  if (i < n) {
    float4 a = *(const float4*)(w1 + i);
    float4 b = *(const float4*)(w2 + i);
    ushort4 ua = { f2bf(a.x), f2bf(a.y), f2bf(a.z), f2bf(a.w) };
    ushort4 ub = { f2bf(b.x), f2bf(b.y), f2bf(b.z), f2bf(b.w) };
    *(ushort4*)(o1 + i) = ua;
    *(ushort4*)(o2 + i) = ub;
  }
}

// out[b,s,:] = concat(x[b,s,:], x@emb_w^T + emb_b) + pos_table[s+1]
__global__ __launch_bounds__(256)
void embed_k(const float* __restrict__ x, const float* __restrict__ ew,
             const float* __restrict__ eb, const float* __restrict__ pos,
             u16* __restrict__ out)
{
  const int rs = blockIdx.x;          // b*512 + s
  const int s  = rs & 511;
  __shared__ float xr[32];
  const int t = threadIdx.x;
  if (t < 32) xr[t] = x[(size_t)rs * 32 + t];
  __syncthreads();
#pragma unroll
  for (int rep = 0; rep < 2; ++rep) {
    const int c = t + rep * 256;
    float v;
    if (c < 32) {
      v = xr[c];
    } else {
      const float* w = ew + (size_t)(c - 32) * 32;
      float acc = eb[c - 32];
#pragma unroll
      for (int f = 0; f < 32; ++f) acc += xr[f] * w[f];
      v = acc;
    }
    v += pos[(size_t)(s + 1) * 512 + c];
    out[(size_t)rs * 512 + c] = f2bf(v);
  }
}

// pad[b,s] = (sum_f x[b,s,f] <= -9999)
__global__ __launch_bounds__(256)
void pad_k(const float* __restrict__ x, unsigned char* __restrict__ pad)
{
  int r = blockIdx.x * 256 + threadIdx.x;
  if (r < TOK) {
    float s = 0.f;
    for (int f = 0; f < 32; ++f) s += x[(size_t)r * 32 + f];
    pad[r] = (s <= -9999.f) ? 1 : 0;
  }
}

// wave-per-row LN(x + y), torch-style (ddof=1, /(std+eps)). 4 rows/block.
__global__ __launch_bounds__(256)
void add_ln(const u16* __restrict__ x, const u16* __restrict__ y,
            const float* __restrict__ g, const float* __restrict__ bb,
            u16* __restrict__ out)
{
  const int row  = blockIdx.x * 4 + (threadIdx.x >> 6);
  const int lane = threadIdx.x & 63;
  const int c0 = lane * 8;
  const size_t base = (size_t)row * Dm + c0;

  uint4 xr = *(const uint4*)(x + base);
  uint4 yr = *(const uint4*)(y + base);
  const u16* xh = (const u16*)&xr;
  const u16* yh = (const u16*)&yr;
  float z[8];
  float s = 0.f;
#pragma unroll
  for (int j = 0; j < 8; ++j) { z[j] = bf2f(xh[j]) + bf2f(yh[j]); s += z[j]; }
#pragma unroll
  for (int off = 32; off > 0; off >>= 1) s += __shfl_xor(s, off);
  const float mean = s * (1.f / 512.f);
  float ss = 0.f;
#pragma unroll
  for (int j = 0; j < 8; ++j) { z[j] -= mean; ss += z[j] * z[j]; }
#pragma unroll
  for (int off = 32; off > 0; off >>= 1) ss += __shfl_xor(ss, off);
  const float stdv = sqrtf(ss * (1.f / 511.f));
  const float inv = 1.f / (stdv + 1e-6f);

  float4 g0 = *(const float4*)(g + c0),  g1 = *(const float4*)(g + c0 + 4);
  float4 b0 = *(const float4*)(bb + c0), b1 = *(const float4*)(bb + c0 + 4);
  float gv[8] = { g0.x, g0.y, g0.z, g0.w, g1.x, g1.y, g1.z, g1.w };
  float bv[8] = { b0.x, b0.y, b0.z, b0.w, b1.x, b1.y, b1.z, b1.w };
  uint4 ow;
  u16* oh = (u16*)&ow;
#pragma unroll
  for (int j = 0; j < 8; ++j) oh[j] = f2bf(gv[j] * z[j] * inv + bv[j]);
  *(uint4*)(out + base) = ow;
}

// bf16 -> fp32 final output, 8 per thread
__global__ __launch_bounds__(256)
void store_f32(const u16* __restrict__ in, float* __restrict__ out, int n)
{
  int i = (blockIdx.x * 256 + threadIdx.x) * 8;
  if (i < n) {
    uint4 raw = *(const uint4*)(in + i);
    const u16* h = (const u16*)&raw;
    float4 o0 = { bf2f(h[0]), bf2f(h[1]), bf2f(h[2]), bf2f(h[3]) };
    float4 o1 = { bf2f(h[4]), bf2f(h[5]), bf2f(h[6]), bf2f(h[7]) };
    *(float4*)(out + i) = o0;
    *(float4*)(out + i + 4) = o1;
  }
}

extern "C" void kernel_launch(void* const* d_in, const int* in_sizes, int n_in,
                              void* d_out, int out_size, void* d_ws, size_t ws_size,
                              hipStream_t stream)
{
  (void)in_sizes; (void)n_in; (void)out_size;
  const float* enc_in   = (const float*)d_in[0];
  const float* dec_in   = (const float*)d_in[1];
  const float* emb_w    = (const float*)d_in[2];
  const float* emb_b    = (const float*)d_in[3];
  const float* pos      = (const float*)d_in[4];
  const float* e_qkv_w  = (const float*)d_in[5];
  const float* e_qkv_b  = (const float*)d_in[6];
  const float* e_pw     = (const float*)d_in[7];
  const float* e_pb     = (const float*)d_in[8];
  const float* e_ln1    = (const float*)d_in[9];
  const float* e_w1     = (const float*)d_in[10];
  const float* e_b1     = (const float*)d_in[11];
  const float* e_w2     = (const float*)d_in[12];
  const float* e_b2     = (const float*)d_in[13];
  const float* e_ln2    = (const float*)d_in[14];
  const float* ds_qkv_w = (const float*)d_in[15];
  const float* ds_qkv_b = (const float*)d_in[16];
  const float* ds_pw    = (const float*)d_in[17];
  const float* ds_pb    = (const float*)d_in[18];
  const float* d_ln1    = (const float*)d_in[19];
  const float* dc_qkv_w = (const float*)d_in[20];
  const float* dc_qkv_b = (const float*)d_in[21];
  const float* dc_pw    = (const float*)d_in[22];
  const float* dc_pb    = (const float*)d_in[23];
  const float* d_ln2    = (const float*)d_in[24];
  const float* d_w1     = (const float*)d_in[25];
  const float* d_b1     = (const float*)d_in[26];
  const float* d_w2     = (const float*)d_in[27];
  const float* d_b2     = (const float*)d_in[28];
  const float* d_ln3    = (const float*)d_in[29];

  u16* ws  = (u16*)d_ws;
  u16* enc = ws;             // EL
  u16* dec = ws + EL;        // EL
  u16* qb  = ws + 2 * EL;    // EL [B,H,S,DK]  (K at +EL, V^T at +2EL: consecutive)
  u16* kb  = ws + 3 * EL;    // EL [B,H,S,DK]
  u16* vT  = ws + 4 * EL;    // EL [B,H,DK,S]
  u16* ctx = ws + 5 * EL;    // EL [B,S,H*DK]
  u16* t1  = ws + 6 * EL;    // EL
  u16* hff = ws + 7 * EL;    // 4*EL [B,S,Dff]
  u16* wf1 = ws + 11 * EL;            // current layer w1 (bf16)
  u16* wf2 = ws + 11 * EL + EL / 2;   // current layer w2 (bf16)
  u16* wT  = ws + 15 * EL;   // 48 transposed bf16 512x512 matrices
  unsigned char* padE = (unsigned char*)(ws + 21 * EL);
  unsigned char* padD = padE + TOK;
  if (ws_size < 21 * EL * 2 + 2 * TOK) return;

  dim3 tb(32, 8);
  transpose512<<<dim3(16, 16, 12), tb, 0, stream>>>(e_qkv_w,  wT);              // [0..11]
  transpose512<<<dim3(16, 16, 12), tb, 0, stream>>>(ds_qkv_w, wT + 12 * MAT);   // [12..23]
  transpose512<<<dim3(16, 16, 12), tb, 0, stream>>>(dc_qkv_w, wT + 24 * MAT);   // [24..35]
  transpose512<<<dim3(16, 16, 4),  tb, 0, stream>>>(e_pw,     wT + 36 * MAT);   // [36..39]
  transpose512<<<dim3(16, 16, 4),  tb, 0, stream>>>(ds_pw,    wT + 40 * MAT);   // [40..43]
  transpose512<<<dim3(16, 16, 4),  tb, 0, stream>>>(dc_pw,    wT + 44 * MAT);   // [44..47]

  embed_k<<<TOK, 256, 0, stream>>>(enc_in, emb_w, emb_b, pos, enc);
  embed_k<<<TOK, 256, 0, stream>>>(dec_in, emb_w, emb_b, pos, dec);
  pad_k<<<TOK / 256, 256, 0, stream>>>(enc_in, padE);
  pad_k<<<TOK / 256, 256, 0, stream>>>(dec_in, padD);

  // full MHA sublayer: x = LN(x + proj(flash_attn(q(x), k(kv), v(kv))))
  auto attention = [&](const u16* qsrc, const u16* kvsrc, const u16* wq3, const float* b3,
                       const u16* pwT, const float* pb, const float* ln,
                       const unsigned char* pad, int mtype, u16* x) {
    if (qsrc == kvsrc) {
      // fused QKV: [4096,512] x [1536,512]^T -> qb/kb/vT
      gemm_tile<64, 128><<<dim3(12, 64, 1), 256, 0, stream>>>(
          qsrc, wq3, b3, qb, 512, 512, 0, 512, 0, 0, 0, 4, 0, 0);
    } else {
      gemm_tile<64, 64><<<dim3(8, 64, 1), 256, 0, stream>>>(
          qsrc, wq3, b3, qb, 512, 512, 0, 512, 0, 0, 0, 4, 0, 0);
      gemm_tile<64, 128><<<dim3(8, 64, 1), 256, 0, stream>>>(
          kvsrc, wq3 + MAT, b3, qb, 512, 512, 0, 512, 0, 0, 0, 4, 0, 512);
    }
    flash_attn<<<dim3(8, 64), 256, 0, stream>>>(qb, kb, vT, pad, ctx, mtype);
    gemm_tile<64, 64><<<dim3(8, 64, 1), 256, 0, stream>>>(
        ctx, pwT, pb, t1, 512, 512, 0, 512, 0, 512, 0, 0, 0, 0);
    add_ln<<<TOK / 4, 256, 0, stream>>>(x, t1, ln, ln + 512, x);
  };

  auto ffn = [&](u16* x, const float* w1, const float* b1, const float* w2,
                 const float* b2, const float* ln) {
    convert2<<<1024, 256, 0, stream>>>(w1, w2, wf1, wf2, Dff * Dm);
    gemm_tile<128, 128><<<dim3(16, 32, 1), 256, 0, stream>>>(
        x, wf1, b1, hff, 512, 512, 0, 512, 0, 2048, 0, 0, 1, 0);
    gemm_tile<64, 64><<<dim3(8, 64, 1), 256, 0, stream>>>(
        hff, wf2, b2, t1, 2048, 2048, 0, 2048, 0, 512, 0, 0, 0, 0);
    add_ln<<<TOK / 4, 256, 0, stream>>>(x, t1, ln, ln + 512, x);
  };

  for (int i = 0; i < NL; ++i) {
    attention(enc, enc, wT + (size_t)(i * 3) * MAT, e_qkv_b + i * 3 * 512,
              wT + (size_t)(36 + i) * MAT, e_pb + i * 512, e_ln1 + i * 1024, padE, 0, enc);
    ffn(enc, e_w1 + (size_t)i * Dff * Dm, e_b1 + i * Dff,
        e_w2 + (size_t)i * Dm * Dff, e_b2 + i * Dm, e_ln2 + i * 1024);
  }

  for (int i = 0; i < NL; ++i) {
    attention(dec, dec, wT + (size_t)(12 + i * 3) * MAT, ds_qkv_b + i * 3 * 512,
              wT + (size_t)(40 + i) * MAT, ds_pb + i * 512, d_ln1 + i * 1024, padD, 1, dec);
    attention(dec, enc, wT + (size_t)(24 + i * 3) * MAT, dc_qkv_b + i * 3 * 512,
              wT + (size_t)(44 + i) * MAT, dc_pb + i * 512, d_ln2 + i * 1024, padE, 2, dec);
    ffn(dec, d_w1 + (size_t)i * Dff * Dm, d_b1 + i * Dff,
        d_w2 + (size_t)i * Dm * Dff, d_b2 + i * Dm, d_ln3 + i * 1024);
  }

  store_f32<<<(int)(EL / 8 / 256), 256, 0, stream>>>(dec, (float*)d_out, (int)EL);
}

// Round 6
// 1298.550 us; speedup vs baseline: 2.9092x; 1.1467x over previous
//
#include <hip/hip_runtime.h>
#include <cstdint>
#include <cstddef>

typedef unsigned short u16;
typedef __bf16 bf16x8 __attribute__((ext_vector_type(8)));
typedef float f32x4 __attribute__((ext_vector_type(4)));

constexpr int Bz = 8, Sq = 512, Hh = 8, DKd = 64, Dm = 512, Dff = 2048, NL = 4;
constexpr int TOK = Bz * Sq;               // 4096 tokens
constexpr size_t MAT = (size_t)512 * 512;  // 262144 elems per 512x512 matrix
constexpr size_t EL  = (size_t)TOK * Dm;   // 2097152 elems per activation tensor
constexpr size_t WFT = (size_t)Dff * Dm;   // 1048576 elems per FFN matrix

__device__ __forceinline__ float bf2f(u16 u) {
  union { uint32_t i; float f; } v; v.i = (uint32_t)u << 16; return v.f;
}
__device__ __forceinline__ u16 f2bf(float f) {
  union { float f; uint32_t i; } v; v.f = f;
  uint32_t i = v.i;
  i += 0x7fffu + ((i >> 16) & 1u);   // round-to-nearest-even
  return (u16)(i >> 16);
}

// async global -> LDS, 16B per lane (global_load_lds_dwordx4)
__device__ __forceinline__ void gload16(const u16* g, u16* l) {
  __builtin_amdgcn_global_load_lds(
      (const __attribute__((address_space(1))) unsigned int*)g,
      (__attribute__((address_space(3))) unsigned int*)l, 16, 0, 0);
}

// ---------------------------------------------------------------------------
// Tiled NT GEMM: C[M,N] = A[M,K] @ Bt[N,K]^T (+bias fp32) (+relu)
// 256 threads = 4 waves (2x2); BK=64 (half the barrier count of BK=32);
// global_load_lds staging, XOR chunk swizzle (c ^= row&7) -> 2-way banks.
// cmode 0: plain write; 4: qkv split (Q scaled 0.125, Q->C [B,H,S,DK],
//          K->C+EL [B,H,S,DK], V->C+2EL transposed [B,H,DK,S]).
// A2/xsplit: blocks with blockIdx.x >= xsplit read A2 and write cols 512+
//            (merged cross-attention Q-proj + KV-proj dispatch).
// ---------------------------------------------------------------------------
template<int BM, int BN>
__global__ __launch_bounds__(256)
void gemm_tile(const u16* __restrict__ A, const u16* __restrict__ Bt,
               const float* __restrict__ bias, u16* __restrict__ C,
               int K, int lda, long long sA, int ldb, long long sB,
               int ldc, long long sC, int cmode, int relu, int colofs,
               const u16* A2, int xsplit)
{
  constexpr int HM = BM / 2, HN = BN / 2, MI = HM / 16, NI = HN / 16;
  __shared__ __align__(16) u16 As[BM * 64];
  __shared__ __align__(16) u16 Bs[BN * 64];
  const int bz = blockIdx.z;
  const u16* Abase = A;
  int colbase;
  if (A2 && (int)blockIdx.x >= xsplit) {
    Abase = A2;
    colbase = 512 + ((int)blockIdx.x - xsplit) * BN;
  } else {
    colbase = colofs + (int)blockIdx.x * BN;
  }
  const u16* Ab = Abase + (size_t)bz * (size_t)sA + (size_t)(blockIdx.y * BM) * lda;
  const u16* Bb = Bt + (size_t)bz * (size_t)sB + (size_t)colbase * ldb;
  const int tid  = threadIdx.x;
  const int lane = tid & 63;
  const int wid  = tid >> 6;
  const int l15  = lane & 15;
  const int quad = lane >> 4;
  const int wm   = wid >> 1, wn = wid & 1;

  f32x4 acc[MI][NI] = {};

  for (int k0 = 0; k0 < K; k0 += 64) {
#pragma unroll
    for (int i = 0; i < BM / 32; ++i) {          // A: BM rows x 64, 8 chunks/row
      const int s = tid + i * 256;
      const int row = s >> 3, c = (s & 7) ^ (row & 7);
      gload16(Ab + (size_t)row * lda + k0 + c * 8, As + s * 8);
    }
#pragma unroll
    for (int i = 0; i < BN / 32; ++i) {
      const int s = tid + i * 256;
      const int row = s >> 3, c = (s & 7) ^ (row & 7);
      gload16(Bb + (size_t)row * ldb + k0 + c * 8, Bs + s * 8);
    }
    __syncthreads();
#pragma unroll
    for (int kk = 0; kk < 2; ++kk) {
      bf16x8 af[MI], bfr[NI];
#pragma unroll
      for (int mi = 0; mi < MI; ++mi) {
        const int ra = wm * HM + mi * 16 + l15;
        af[mi] = *(const bf16x8*)(As + ra * 64 + (((kk * 4 + quad) ^ (ra & 7))) * 8);
      }
#pragma unroll
      for (int ni = 0; ni < NI; ++ni) {
        const int rb = wn * HN + ni * 16 + l15;
        bfr[ni] = *(const bf16x8*)(Bs + rb * 64 + (((kk * 4 + quad) ^ (rb & 7))) * 8);
      }
#pragma unroll
      for (int mi = 0; mi < MI; ++mi)
#pragma unroll
        for (int ni = 0; ni < NI; ++ni)
          acc[mi][ni] = __builtin_amdgcn_mfma_f32_16x16x32_bf16(af[mi], bfr[ni], acc[mi][ni], 0, 0, 0);
    }
    __syncthreads();
  }

  const int rblk = blockIdx.y * BM + wm * HM + quad * 4;
#pragma unroll
  for (int ni = 0; ni < NI; ++ni) {
    const int colx = colbase + wn * HN + ni * 16 + l15;
    const float bv = bias ? bias[colx] : 0.f;
#pragma unroll
    for (int mi = 0; mi < MI; ++mi) {
#pragma unroll
      for (int r = 0; r < 4; ++r) {
        float v = acc[mi][ni][r] + bv;
        if (relu) v = fmaxf(v, 0.f);
        const int grow = rblk + mi * 16 + r;
        size_t off;
        if (cmode == 0) {
          off = (size_t)bz * (size_t)sC + (size_t)grow * ldc + colx;
        } else {  // 4: qkv scatter; fold 1/sqrt(DK)=0.125 into Q
          const int sec = colx >> 9, n = colx & 511, h = n >> 6, d = n & 63;
          const int b = grow >> 9, s = grow & 511;
          if (sec == 0) v *= 0.125f;
          if (sec < 2) off = (size_t)sec * EL + (size_t)b * 262144 + (size_t)h * 32768 + (size_t)s * 64 + d;
          else         off = 2 * EL + (size_t)b * 262144 + (size_t)h * 32768 + (size_t)d * 512 + s;
        }
        C[off] = f2bf(v);
      }
    }
  }
}

// ---------------------------------------------------------------------------
// Fused attention: per block = (q-tile of 64 rows, one (b,h)).
// ctx[b,s,h*64+d] = softmax(mask(Q K^T)) V.  Q pre-scaled by 0.125.
// ---------------------------------------------------------------------------
__global__ __launch_bounds__(256)
void flash_attn(const u16* __restrict__ q, const u16* __restrict__ k,
                const u16* __restrict__ v, const unsigned char* __restrict__ pad,
                u16* __restrict__ ctx, int mtype)
{
  __shared__ __align__(16) u16 KVs[8192];      // 16 KB: K or V chunk (swizzled)
  __shared__ __align__(16) u16 Pw[4][2048];    // 4 KB per wave: P tile 16x128
  const int bh = blockIdx.y, b = bh >> 3, h = bh & 7;
  const int qt = blockIdx.x;
  const int tid = threadIdx.x, lane = tid & 63, wid = tid >> 6;
  const int l15 = lane & 15, quad = lane >> 4;
  const size_t bho = (size_t)bh * 32768;
  const int qrow = qt * 64 + wid * 16 + l15;       // A-operand row (this lane)
  const int qcd  = qt * 64 + wid * 16 + quad * 4;  // C-layout row base

  unsigned char* Ps = (unsigned char*)&Pw[0][0];
  if (tid < 128) ((uchar4*)Ps)[tid] = ((const uchar4*)(pad + b * 512))[tid];

  bf16x8 aq0 = *(const bf16x8*)(q + bho + (size_t)qrow * 64 + quad * 8);
  bf16x8 aq1 = *(const bf16x8*)(q + bho + (size_t)qrow * 64 + 32 + quad * 8);

  f32x4 S[32];
#pragma unroll
  for (int kc = 0; kc < 4; ++kc) {
    __syncthreads();
#pragma unroll
    for (int i = 0; i < 4; ++i) {             // stage K chunk [128 keys][64]
      const int s = tid + i * 256;
      const int row = s >> 3, c = (s & 7) ^ (row & 7);
      gload16(k + bho + (size_t)(kc * 128 + row) * 64 + c * 8, KVs + s * 8);
    }
    __syncthreads();
#pragma unroll
    for (int t = 0; t < 8; ++t) {
      const int sw = l15 & 7;
      bf16x8 b0 = *(const bf16x8*)(KVs + (t * 16 + l15) * 64 + (quad ^ sw) * 8);
      bf16x8 b1 = *(const bf16x8*)(KVs + (t * 16 + l15) * 64 + ((4 + quad) ^ sw) * 8);
      f32x4 z = {0.f, 0.f, 0.f, 0.f};
      z = __builtin_amdgcn_mfma_f32_16x16x32_bf16(aq0, b0, z, 0, 0, 0);
      S[kc * 8 + t] = __builtin_amdgcn_mfma_f32_16x16x32_bf16(aq1, b1, z, 0, 0, 0);
    }
  }

  unsigned pm = 0u;
#pragma unroll
  for (int t = 0; t < 32; ++t) pm |= (unsigned)(Ps[t * 16 + l15] != 0) << t;

  float inv[4];
#pragma unroll
  for (int r = 0; r < 4; ++r) {
    const int qg = qcd + r;
    float mx = -3.0e38f;
#pragma unroll
    for (int t = 0; t < 32; ++t) {
      const int col = t * 16 + l15;
      const bool m = ((pm >> t) & 1u) || (mtype == 1 && col > qg);
      const float val = m ? -1e9f : S[t][r];
      S[t][r] = val;
      mx = fmaxf(mx, val);
    }
#pragma unroll
    for (int o = 8; o > 0; o >>= 1) mx = fmaxf(mx, __shfl_xor(mx, o));
    float sm = 0.f;
#pragma unroll
    for (int t = 0; t < 32; ++t) { const float e = __expf(S[t][r] - mx); S[t][r] = e; sm += e; }
#pragma unroll
    for (int o = 8; o > 0; o >>= 1) sm += __shfl_xor(sm, o);
    inv[r] = 1.f / sm;
  }

  f32x4 O[4] = {};
  u16* myP = &Pw[wid][0];
#pragma unroll
  for (int kc = 0; kc < 4; ++kc) {
    __syncthreads();
#pragma unroll
    for (int i = 0; i < 4; ++i) {             // stage V chunk [64 dk][128 keys]
      const int s = tid + i * 256;
      const int row = s >> 4, c = (s & 15) ^ (row & 15);
      gload16(v + bho + (size_t)row * 512 + kc * 128 + c * 8, KVs + s * 8);
    }
#pragma unroll
    for (int t = 0; t < 8; ++t)
#pragma unroll
      for (int r = 0; r < 4; ++r) {
        const int rowq = quad * 4 + r;
        const int c = 2 * t + (l15 >> 3);
        myP[rowq * 128 + (c ^ rowq) * 8 + (l15 & 7)] = f2bf(S[kc * 8 + t][r] * inv[r]);
      }
    __syncthreads();
#pragma unroll
    for (int kk = 0; kk < 4; ++kk) {
      bf16x8 ap = *(const bf16x8*)(myP + l15 * 128 + ((kk * 4 + quad) ^ l15) * 8);
#pragma unroll
      for (int ni = 0; ni < 4; ++ni) {
        bf16x8 bv = *(const bf16x8*)(KVs + (ni * 16 + l15) * 128 + ((kk * 4 + quad) ^ l15) * 8);
        O[ni] = __builtin_amdgcn_mfma_f32_16x16x32_bf16(ap, bv, O[ni], 0, 0, 0);
      }
    }
  }

  const int token = b * 512 + qcd;
#pragma unroll
  for (int ni = 0; ni < 4; ++ni)
#pragma unroll
    for (int r = 0; r < 4; ++r)
      ctx[(size_t)(token + r) * 512 + h * 64 + ni * 16 + l15] = f2bf(O[ni][r]);
}

// all 48 weight transposes in one dispatch (fp32 [K,N] -> bf16 [N,K])
__global__ __launch_bounds__(256)
void transpose_all(const float* __restrict__ s0, const float* __restrict__ s1,
                   const float* __restrict__ s2, const float* __restrict__ s3,
                   const float* __restrict__ s4, const float* __restrict__ s5,
                   u16* __restrict__ out)
{
  __shared__ float tile[32][33];
  const int z = blockIdx.z;
  const float* src; int zi;
  if      (z < 12) { src = s0; zi = z; }
  else if (z < 24) { src = s1; zi = z - 12; }
  else if (z < 36) { src = s2; zi = z - 24; }
  else if (z < 40) { src = s3; zi = z - 36; }
  else if (z < 44) { src = s4; zi = z - 40; }
  else             { src = s5; zi = z - 44; }
  const float* in = src + (size_t)zi * MAT;
  u16* o = out + (size_t)z * MAT;
  int x = blockIdx.x * 32 + threadIdx.x;
  int y = blockIdx.y * 32 + threadIdx.y;
#pragma unroll
  for (int i = 0; i < 32; i += 8)
    tile[threadIdx.y + i][threadIdx.x] = in[(size_t)(y + i) * 512 + x];
  __syncthreads();
  x = blockIdx.y * 32 + threadIdx.x;
  y = blockIdx.x * 32 + threadIdx.y;
#pragma unroll
  for (int i = 0; i < 32; i += 8)
    o[(size_t)(y + i) * 512 + x] = f2bf(tile[threadIdx.x][threadIdx.y + i]);
}

// convert 4 fp32 tensors (n elems each) -> bf16, packed consecutively in out
__global__ __launch_bounds__(256)
void convert4(const float* __restrict__ a, const float* __restrict__ b,
              const float* __restrict__ c, const float* __restrict__ d,
              u16* __restrict__ out, int n)
{
  const float* srcs[4] = { a, b, c, d };
  const float* src = srcs[blockIdx.y];
  u16* dst = out + (size_t)blockIdx.y * n;
  int i = (blockIdx.x * 256 + threadIdx.x) * 4;
  if (i < n) {
    float4 v = *(const float4*)(src + i);
    ushort4 u = { f2bf(v.x), f2bf(v.y), f2bf(v.z), f2bf(v.w) };
    *(ushort4*)(dst + i) = u;
  }
}

// out[b,s,:] = concat(x[b,s,:], x@emb_w^T + emb_b) + pos_table[s+1]; also pad[b,s]
__global__ __launch_bounds__(256)
void embed_k(const float* __restrict__ x, const float* __restrict__ ew,
             const float* __restrict__ eb, const float* __restrict__ pos,
             u16* __restrict__ out, unsigned char* __restrict__ padv)
{
  const int rs = blockIdx.x;          // b*512 + s
  const int s  = rs & 511;
  __shared__ float xr[32];
  const int t = threadIdx.x;
  if (t < 32) xr[t] = x[(size_t)rs * 32 + t];
  __syncthreads();
  if (t == 0) {
    float sacc = 0.f;
#pragma unroll
    for (int f = 0; f < 32; ++f) sacc += xr[f];
    padv[rs] = (sacc <= -9999.f) ? 1 : 0;
  }
#pragma unroll
  for (int rep = 0; rep < 2; ++rep) {
    const int c = t + rep * 256;
    float v;
    if (c < 32) {
      v = xr[c];
    } else {
      const float* w = ew + (size_t)(c - 32) * 32;
      float acc = eb[c - 32];
#pragma unroll
      for (int f = 0; f < 32; ++f) acc += xr[f] * w[f];
      v = acc;
    }
    v += pos[(size_t)(s + 1) * 512 + c];
    out[(size_t)rs * 512 + c] = f2bf(v);
  }
}

// wave-per-row LN(x + y), torch-style (ddof=1, /(std+eps)). 4 rows/block.
__global__ __launch_bounds__(256)
void add_ln(const u16* __restrict__ x, const u16* __restrict__ y,
            const float* __restrict__ g, const float* __restrict__ bb,
            u16* __restrict__ out)
{
  const int row  = blockIdx.x * 4 + (threadIdx.x >> 6);
  const int lane = threadIdx.x & 63;
  const int c0 = lane * 8;
  const size_t base = (size_t)row * Dm + c0;

  uint4 xr = *(const uint4*)(x + base);
  uint4 yr = *(const uint4*)(y + base);
  const u16* xh = (const u16*)&xr;
  const u16* yh = (const u16*)&yr;
  float z[8];
  float s = 0.f;
#pragma unroll
  for (int j = 0; j < 8; ++j) { z[j] = bf2f(xh[j]) + bf2f(yh[j]); s += z[j]; }
#pragma unroll
  for (int off = 32; off > 0; off >>= 1) s += __shfl_xor(s, off);
  const float mean = s * (1.f / 512.f);
  float ss = 0.f;
#pragma unroll
  for (int j = 0; j < 8; ++j) { z[j] -= mean; ss += z[j] * z[j]; }
#pragma unroll
  for (int off = 32; off > 0; off >>= 1) ss += __shfl_xor(ss, off);
  const float stdv = sqrtf(ss * (1.f / 511.f));
  const float inv = 1.f / (stdv + 1e-6f);

  float4 g0 = *(const float4*)(g + c0),  g1 = *(const float4*)(g + c0 + 4);
  float4 b0 = *(const float4*)(bb + c0), b1 = *(const float4*)(bb + c0 + 4);
  float gv[8] = { g0.x, g0.y, g0.z, g0.w, g1.x, g1.y, g1.z, g1.w };
  float bv[8] = { b0.x, b0.y, b0.z, b0.w, b1.x, b1.y, b1.z, b1.w };
  uint4 ow;
  u16* oh = (u16*)&ow;
#pragma unroll
  for (int j = 0; j < 8; ++j) oh[j] = f2bf(gv[j] * z[j] * inv + bv[j]);
  *(uint4*)(out + base) = ow;
}

// bf16 -> fp32 final output, 8 per thread
__global__ __launch_bounds__(256)
void store_f32(const u16* __restrict__ in, float* __restrict__ out, int n)
{
  int i = (blockIdx.x * 256 + threadIdx.x) * 8;
  if (i < n) {
    uint4 raw = *(const uint4*)(in + i);
    const u16* h = (const u16*)&raw;
    float4 o0 = { bf2f(h[0]), bf2f(h[1]), bf2f(h[2]), bf2f(h[3]) };
    float4 o1 = { bf2f(h[4]), bf2f(h[5]), bf2f(h[6]), bf2f(h[7]) };
    *(float4*)(out + i) = o0;
    *(float4*)(out + i + 4) = o1;
  }
}

extern "C" void kernel_launch(void* const* d_in, const int* in_sizes, int n_in,
                              void* d_out, int out_size, void* d_ws, size_t ws_size,
                              hipStream_t stream)
{
  (void)in_sizes; (void)n_in; (void)out_size;
  const float* enc_in   = (const float*)d_in[0];
  const float* dec_in   = (const float*)d_in[1];
  const float* emb_w    = (const float*)d_in[2];
  const float* emb_b    = (const float*)d_in[3];
  const float* pos      = (const float*)d_in[4];
  const float* e_qkv_w  = (const float*)d_in[5];
  const float* e_qkv_b  = (const float*)d_in[6];
  const float* e_pw     = (const float*)d_in[7];
  const float* e_pb     = (const float*)d_in[8];
  const float* e_ln1    = (const float*)d_in[9];
  const float* e_w1     = (const float*)d_in[10];
  const float* e_b1     = (const float*)d_in[11];
  const float* e_w2     = (const float*)d_in[12];
  const float* e_b2     = (const float*)d_in[13];
  const float* e_ln2    = (const float*)d_in[14];
  const float* ds_qkv_w = (const float*)d_in[15];
  const float* ds_qkv_b = (const float*)d_in[16];
  const float* ds_pw    = (const float*)d_in[17];
  const float* ds_pb    = (const float*)d_in[18];
  const float* d_ln1    = (const float*)d_in[19];
  const float* dc_qkv_w = (const float*)d_in[20];
  const float* dc_qkv_b = (const float*)d_in[21];
  const float* dc_pw    = (const float*)d_in[22];
  const float* dc_pb    = (const float*)d_in[23];
  const float* d_ln2    = (const float*)d_in[24];
  const float* d_w1     = (const float*)d_in[25];
  const float* d_b1     = (const float*)d_in[26];
  const float* d_w2     = (const float*)d_in[27];
  const float* d_b2     = (const float*)d_in[28];
  const float* d_ln3    = (const float*)d_in[29];

  u16* ws  = (u16*)d_ws;
  u16* enc = ws;             // EL
  u16* dec = ws + EL;        // EL
  u16* qb  = ws + 2 * EL;    // EL [B,H,S,DK]  (K at +EL, V^T at +2EL)
  u16* kb  = ws + 3 * EL;    // EL [B,H,S,DK]
  u16* vT  = ws + 4 * EL;    // EL [B,H,DK,S]
  u16* ctx = ws + 5 * EL;    // EL [B,S,H*DK]
  u16* t1  = ws + 6 * EL;    // EL
  u16* hff = ws + 7 * EL;    // 4*EL [B,S,Dff]
  u16* wT  = ws + 15 * EL;   // 6*EL: 48 transposed bf16 512x512 matrices
  unsigned char* padE = (unsigned char*)(ws + 21 * EL);
  unsigned char* padD = padE + TOK;
  u16* wfAll = ws + 22 * EL; // 8*EL: [e_w1(4L), e_w2(4L), d_w1(4L), d_w2(4L)] bf16
  if (ws_size < 30 * EL * 2 + 2 * TOK) return;

  transpose_all<<<dim3(16, 16, 48), dim3(32, 8), 0, stream>>>(
      e_qkv_w, ds_qkv_w, dc_qkv_w, e_pw, ds_pw, dc_pw, wT);
  convert4<<<dim3(4096, 4), 256, 0, stream>>>(e_w1, e_w2, d_w1, d_w2, wfAll, (int)(4 * WFT));
  embed_k<<<TOK, 256, 0, stream>>>(enc_in, emb_w, emb_b, pos, enc, padE);
  embed_k<<<TOK, 256, 0, stream>>>(dec_in, emb_w, emb_b, pos, dec, padD);

  // full MHA sublayer: x = LN(x + proj(flash_attn(q(qsrc), k(kvsrc), v(kvsrc))))
  auto attention = [&](const u16* qsrc, const u16* kvsrc, const u16* wq3, const float* b3,
                       const u16* pwT, const float* pb, const float* ln,
                       const unsigned char* pad, int mtype, u16* x) {
    if (qsrc == kvsrc) {
      // fused QKV: [4096,512] x [1536,512]^T -> qb/kb/vT
      gemm_tile<64, 128><<<dim3(12, 64, 1), 256, 0, stream>>>(
          qsrc, wq3, b3, qb, 512, 512, 0, 512, 0, 0, 0, 4, 0, 0, nullptr, 0);
    } else {
      // merged cross Q (x<4: A=qsrc, cols 0..511) + KV (x>=4: A=kvsrc, cols 512..1535)
      gemm_tile<64, 128><<<dim3(12, 64, 1), 256, 0, stream>>>(
          qsrc, wq3, b3, qb, 512, 512, 0, 512, 0, 0, 0, 4, 0, 0, kvsrc, 4);
    }
    flash_attn<<<dim3(8, 64), 256, 0, stream>>>(qb, kb, vT, pad, ctx, mtype);
    gemm_tile<64, 64><<<dim3(8, 64, 1), 256, 0, stream>>>(
        ctx, pwT, pb, t1, 512, 512, 0, 512, 0, 512, 0, 0, 0, 0, nullptr, 0);
    add_ln<<<TOK / 4, 256, 0, stream>>>(x, t1, ln, ln + 512, x);
  };

  auto ffn = [&](u16* x, const u16* w1b, const float* b1, const u16* w2b,
                 const float* b2, const float* ln) {
    gemm_tile<128, 128><<<dim3(16, 32, 1), 256, 0, stream>>>(
        x, w1b, b1, hff, 512, 512, 0, 512, 0, 2048, 0, 0, 1, 0, nullptr, 0);
    gemm_tile<64, 64><<<dim3(8, 64, 1), 256, 0, stream>>>(
        hff, w2b, b2, t1, 2048, 2048, 0, 2048, 0, 512, 0, 0, 0, 0, nullptr, 0);
    add_ln<<<TOK / 4, 256, 0, stream>>>(x, t1, ln, ln + 512, x);
  };

  for (int i = 0; i < NL; ++i) {
    attention(enc, enc, wT + (size_t)(i * 3) * MAT, e_qkv_b + i * 3 * 512,
              wT + (size_t)(36 + i) * MAT, e_pb + i * 512, e_ln1 + i * 1024, padE, 0, enc);
    ffn(enc, wfAll + (size_t)i * WFT, e_b1 + i * Dff,
        wfAll + 4 * WFT + (size_t)i * WFT, e_b2 + i * Dm, e_ln2 + i * 1024);
  }

  for (int i = 0; i < NL; ++i) {
    attention(dec, dec, wT + (size_t)(12 + i * 3) * MAT, ds_qkv_b + i * 3 * 512,
              wT + (size_t)(40 + i) * MAT, ds_pb + i * 512, d_ln1 + i * 1024, padD, 1, dec);
    attention(dec, enc, wT + (size_t)(24 + i * 3) * MAT, dc_qkv_b + i * 3 * 512,
              wT + (size_t)(44 + i) * MAT, dc_pb + i * 512, d_ln2 + i * 1024, padE, 2, dec);
    ffn(dec, wfAll + 8 * WFT + (size_t)i * WFT, d_b1 + i * Dff,
        wfAll + 12 * WFT + (size_t)i * WFT, d_b2 + i * Dm, d_ln3 + i * 1024);
  }

  store_f32<<<(int)(EL / 8 / 256), 256, 0, stream>>>(dec, (float*)d_out, (int)EL);
}